// Round 4
// baseline (23745.956 us; speedup 1.0000x reference)
//
#include <hip/hip_runtime.h>
#include <hip/hip_bf16.h>
#include <cstdint>
#include <cstddef>

typedef __hip_bfloat16 bf16;
#define DEVI __device__ __forceinline__

static DEVI float b2f(bf16 v) { return __bfloat162float(v); }

// dtype-robust input load: element i of p, f32 flag chooses interpretation
static DEVI float ldin(const void* p, size_t i, int f32) {
  return f32 ? ((const float*)p)[i] : b2f(((const bf16*)p)[i]);
}

// Problem constants (fixed by setup_inputs)
constexpr int Bb  = 2;
constexpr int Ll  = 6273;    // 1 + 8*28*28
constexpr int NHh = 8;
constexpr int Gg  = 16;      // B*NH
constexpr int Pp  = 1568;    // 8*14*14
constexpr int LL2 = 1569;    // 1 + Pp

// ---------------------------------------------------------------------------
// Input dtype sniffer: true-bf16 N(0,1) data has no huge-exponent halves;
// f32 data read as uint16 halves has ~23% with exponent >= 198 (|v|>2^71).
// Round-3 result proved this fires flag=1 (inputs are f32); kept for safety.
// ---------------------------------------------------------------------------
__global__ void sniff_kernel(const void* x, int* flags) {
  __shared__ int cnt;
  if (threadIdx.x == 0) cnt = 0;
  __syncthreads();
  const unsigned short* u = (const unsigned short*)x;
  int wild = 0;
  for (int i = threadIdx.x; i < 1024; i += 256) {
    int e = (u[i] >> 7) & 0xFF;
    if (e >= 0xC6) wild++;
  }
  atomicAdd(&cnt, wild);
  __syncthreads();
  if (threadIdx.x == 0) flags[0] = (cnt > 16) ? 1 : 0;
}

// ---------------------------------------------------------------------------
// Shared 64x64-tile f32 GEMM inner loop: 256 threads, 4x4 per thread.
// ---------------------------------------------------------------------------
DEVI void mm_inner(const float (*As)[68], const float (*Bs)[68],
                   int tx, int ty, float (&acc)[4][4]) {
  #pragma unroll
  for (int kk = 0; kk < 16; ++kk) {
    float a[4], b[4];
    #pragma unroll
    for (int i = 0; i < 4; ++i) a[i] = As[kk][ty * 4 + i];
    #pragma unroll
    for (int j = 0; j < 4; ++j) b[j] = Bs[kk][tx * 4 + j];
    #pragma unroll
    for (int i = 0; i < 4; ++i)
      #pragma unroll
      for (int j = 0; j < 4; ++j)
        acc[i][j] = fmaf(a[i], b[j], acc[i][j]);
  }
}

// ---------------------------------------------------------------------------
// Positional embedding with a zero row prepended: embz[0,:]=0, embz[1+p,:]=emb[p,:]
// T2=8,H2=14,W2=14, D=512, dt=170 (half 85), dw=172 (half 86)
// ---------------------------------------------------------------------------
__global__ void emb_kernel(float* __restrict__ embz) {
  int idx = blockIdx.x * 256 + threadIdx.x;
  if (idx >= LL2 * 512) return;
  int p = idx >> 9, d = idx & 511;
  float v = 0.f;
  if (p > 0) {
    int pb = p - 1;
    int t = pb / 196, r = pb % 196;
    int h = r / 14, w = r % 14;
    int pos, j, half;
    if (d < 170)      { pos = t; j = d;       half = 85; }
    else if (d < 340) { pos = h; j = d - 170; half = 85; }
    else              { pos = w; j = d - 340; half = 86; }
    int jj = (j < half) ? j : (j - half);
    float omega = powf(10000.f, -(float)jj / (float)half);
    float ang = (float)pos * omega;
    v = (j < half) ? sinf(ang) : cosf(ang);
  }
  embz[idx] = v;
}

// ---------------------------------------------------------------------------
// Per-(b,head) projection: out[l, n] = sum_k x[xoff + l*512 + k]*W[woff + n*512 + k] + b
// M=6273, N=512, K=512. out f32 row-major.
// ---------------------------------------------------------------------------
__global__ void proj_g_kernel(const void* __restrict__ x, size_t xoff,
                              const void* __restrict__ W, size_t woff,
                              const void* __restrict__ bias, size_t boff,
                              const int* __restrict__ flags, float* __restrict__ out) {
  __shared__ float As[16][68];
  __shared__ float Bs[16][68];
  const int M = Ll;
  int f32 = flags[0];
  int m0 = blockIdx.x * 64, n0 = blockIdx.y * 64;
  int tid = threadIdx.x;
  int tx = tid & 15, ty = tid >> 4;
  int lm = tid >> 2, lk4 = (tid & 3) * 4;
  int am = m0 + lm; if (am >= M) am = M - 1;
  float acc[4][4] = {};
  for (int k0 = 0; k0 < 512; k0 += 16) {
    size_t ai = xoff + (size_t)am * 512 + k0 + lk4;
    size_t bi = woff + (size_t)(n0 + lm) * 512 + k0 + lk4;
    #pragma unroll
    for (int c = 0; c < 4; ++c) As[lk4 + c][lm] = ldin(x, ai + c, f32);
    #pragma unroll
    for (int c = 0; c < 4; ++c) Bs[lk4 + c][lm] = ldin(W, bi + c, f32);
    __syncthreads();
    mm_inner(As, Bs, tx, ty, acc);
    __syncthreads();
  }
  #pragma unroll
  for (int i = 0; i < 4; ++i) {
    int m = m0 + ty * 4 + i;
    if (m >= M) continue;
    float* op = out + (size_t)m * 512 + n0 + tx * 4;
    #pragma unroll
    for (int j = 0; j < 4; ++j)
      op[j] = acc[i][j] + ldin(bias, boff + n0 + tx * 4 + j, f32);
  }
}

// ---------------------------------------------------------------------------
// Pool as gathered GEMM. Rows r: g=r/1568, pb=r%1568 -> (t,h2,w2).
// Out[g, 1+pb, n] = sum_{tap,i} In[g,lrow(tap),i]*Wp[n,i,tap]
// Wp layout (O=512, I=512, 1, 2, 2) -> Wp[n*2048 + i*4 + tap]; K = tap*512+i.
// inFlagged: 1 -> In is a harness input (dtype per flag); 0 -> In is f32 scratch
// ---------------------------------------------------------------------------
__global__ void pool_kernel(const void* __restrict__ In, int inFlagged,
                            const void* __restrict__ Wp,
                            const int* __restrict__ flags,
                            float* __restrict__ Out, int Mtot) {
  __shared__ float As[16][68];
  __shared__ float Bs[16][68];
  int wf = flags[0];
  int inf = inFlagged ? wf : 1;
  int m0 = blockIdx.x * 64, n0 = blockIdx.y * 64;
  int tid = threadIdx.x;
  int tx = tid & 15, ty = tid >> 4;
  int lm = tid >> 2, lk4 = (tid & 3) * 4;
  int ar = m0 + lm; if (ar >= Mtot) ar = Mtot - 1;
  int g = ar / Pp, pb = ar % Pp;
  int t = pb / 196, rr = pb % 196;
  int h2 = rr / 14, w2 = rr % 14;
  int l0 = 1 + t * 784 + (2 * h2) * 28 + 2 * w2;
  size_t inbase = (size_t)g * Ll * 512;
  float acc[4][4] = {};
  for (int k0 = 0; k0 < 2048; k0 += 16) {
    int tap = k0 >> 9;
    int lrow = l0 + (tap >> 1) * 28 + (tap & 1);
    int i0 = (k0 & 511) + lk4;
    size_t ai = inbase + (size_t)lrow * 512 + i0;
    size_t bi = (size_t)(n0 + lm) * 2048 + (size_t)i0 * 4 + tap;
    #pragma unroll
    for (int c = 0; c < 4; ++c) As[lk4 + c][lm] = ldin(In, ai + c, inf);
    #pragma unroll
    for (int c = 0; c < 4; ++c) Bs[lk4 + c][lm] = ldin(Wp, bi + 4 * c, wf);
    __syncthreads();
    mm_inner(As, Bs, tx, ty, acc);
    __syncthreads();
  }
  #pragma unroll
  for (int i = 0; i < 4; ++i) {
    int r = m0 + ty * 4 + i;
    if (r >= Mtot) continue;
    int gg = r / Pp, pp = r % Pp;
    float* op = Out + ((size_t)gg * LL2 + 1 + pp) * 512 + n0 + tx * 4;
    #pragma unroll
    for (int j = 0; j < 4; ++j) op[j] = acc[i][j];
  }
}

// cls token passthrough: Out[g,0,:] = In[g,0,:]
__global__ void cls_copy(const void* __restrict__ In, int inFlagged,
                         const int* __restrict__ flags,
                         float* __restrict__ Out, int G) {
  int idx = blockIdx.x * 256 + threadIdx.x;
  if (idx >= G * 512) return;
  int inf = inFlagged ? flags[0] : 1;
  int g = idx >> 9, d = idx & 511;
  Out[(size_t)g * LL2 * 512 + d] = ldin(In, (size_t)g * Ll * 512 + d, inf);
}

// PKg <- scale*PKg + embz   (single head)
__global__ void pk_transform_g(float* __restrict__ PK, const float* __restrict__ embz) {
  int idx = blockIdx.x * 256 + threadIdx.x;
  if (idx >= LL2 * 512) return;
  const float scale = 0.04419417382415922f;  // 512^-0.5
  PK[idx] = PK[idx] * scale + embz[idx];
}

// logits[q,k] = sum_d PQ[q,d] * PKt[k,d]    (single head)
__global__ void logits_kernel(const float* __restrict__ PQ, const float* __restrict__ PKt,
                              float* __restrict__ Lg) {
  __shared__ float As[16][68];
  __shared__ float Bs[16][68];
  int m0 = blockIdx.x * 64, n0 = blockIdx.y * 64;
  int tid = threadIdx.x;
  int tx = tid & 15, ty = tid >> 4;
  int lm = tid >> 2, lk4 = (tid & 3) * 4;
  int am = m0 + lm; if (am >= LL2) am = LL2 - 1;
  int bn = n0 + lm; if (bn >= LL2) bn = LL2 - 1;
  float acc[4][4] = {};
  for (int k0 = 0; k0 < 512; k0 += 16) {
    const float* ap = PQ  + (size_t)am * 512 + k0 + lk4;
    const float* bp = PKt + (size_t)bn * 512 + k0 + lk4;
    #pragma unroll
    for (int c = 0; c < 4; ++c) As[lk4 + c][lm] = ap[c];
    #pragma unroll
    for (int c = 0; c < 4; ++c) Bs[lk4 + c][lm] = bp[c];
    __syncthreads();
    mm_inner(As, Bs, tx, ty, acc);
    __syncthreads();
  }
  #pragma unroll
  for (int i = 0; i < 4; ++i) {
    int m = m0 + ty * 4 + i;
    if (m >= LL2) continue;
    #pragma unroll
    for (int j = 0; j < 4; ++j) {
      int n = n0 + tx * 4 + j;
      if (n < LL2) Lg[(size_t)m * LL2 + n] = acc[i][j];
    }
  }
}

// Row 0 got the positional term from the folded PK; remove:
// logits[0,k] -= dot(PQ[0,:], embz[k,:]).  One wave per k.
__global__ void fixup_row0(const float* __restrict__ PQ, const float* __restrict__ embz,
                           float* __restrict__ Lg) {
  int k = blockIdx.x;
  int lane = threadIdx.x;
  const float* e = embz + (size_t)k * 512;
  float s = 0.f;
  for (int d = lane; d < 512; d += 64) s += PQ[d] * e[d];
  #pragma unroll
  for (int off = 32; off > 0; off >>= 1) s += __shfl_down(s, off, 64);
  if (lane == 0) Lg[k] -= s;
}

// In-place softmax over last dim (1569), one block per row
__global__ void softmax_kernel(float* __restrict__ Lg) {
  int row = blockIdx.x;
  float* p = Lg + (size_t)row * LL2;
  __shared__ float red[256];
  int tid = threadIdx.x;
  float m = -1e30f;
  for (int j = tid; j < LL2; j += 256) m = fmaxf(m, p[j]);
  red[tid] = m; __syncthreads();
  for (int s = 128; s > 0; s >>= 1) { if (tid < s) red[tid] = fmaxf(red[tid], red[tid + s]); __syncthreads(); }
  m = red[0]; __syncthreads();
  float sum = 0.f;
  for (int j = tid; j < LL2; j += 256) { float e = expf(p[j] - m); p[j] = e; sum += e; }
  red[tid] = sum; __syncthreads();
  for (int s = 128; s > 0; s >>= 1) { if (tid < s) red[tid] += red[tid + s]; __syncthreads(); }
  float inv = 1.f / red[0];
  for (int j = tid; j < LL2; j += 256) p[j] *= inv;
}

// Outb_g[q,:] = attn[q,:] @ PV + (q==0 ? 1 : 2) * PQ[q,:]   (single head)
__global__ void av_kernel(const float* __restrict__ Lg, const float* __restrict__ PV,
                          const float* __restrict__ PQ, float* __restrict__ Outb) {
  __shared__ float As[16][68];
  __shared__ float Bs[16][68];
  int m0 = blockIdx.x * 64, n0 = blockIdx.y * 64;
  int tid = threadIdx.x;
  int tx = tid & 15, ty = tid >> 4;
  int lm = tid >> 2, lk4 = (tid & 3) * 4;
  int bkk = tid >> 4, bn4 = (tid & 15) * 4;
  int am = m0 + lm; if (am >= LL2) am = LL2 - 1;
  float acc[4][4] = {};
  for (int k0 = 0; k0 < LL2; k0 += 16) {
    #pragma unroll
    for (int c = 0; c < 4; ++c) {
      int k = k0 + lk4 + c;
      As[lk4 + c][lm] = (k < LL2) ? Lg[(size_t)am * LL2 + k] : 0.f;
    }
    {
      int k = k0 + bkk;
      const float* bp = PV + (size_t)k * 512 + n0 + bn4;
      #pragma unroll
      for (int c = 0; c < 4; ++c)
        Bs[bkk][bn4 + c] = (k < LL2) ? bp[c] : 0.f;
    }
    __syncthreads();
    mm_inner(As, Bs, tx, ty, acc);
    __syncthreads();
  }
  #pragma unroll
  for (int i = 0; i < 4; ++i) {
    int m = m0 + ty * 4 + i;
    if (m >= LL2) continue;
    float rs = (m == 0) ? 1.f : 2.f;
    const float* pq = PQ   + (size_t)m * 512 + n0 + tx * 4;
    float*       op = Outb + (size_t)m * 512 + n0 + tx * 4;
    #pragma unroll
    for (int j = 0; j < 4; ++j) op[j] = acc[i][j] + rs * pq[j];
  }
}

// Y[b,q,dm] = sum_c stacked[b,q,c]*Wd[dm,c] + bd[dm] + PX[b,q,dm]
// stacked[b,q,n*512+d] = Outb[(b*8+n)*L2 + q, d]
__global__ void final_kernel(const float* __restrict__ Outb, const void* __restrict__ Wd,
                             const void* __restrict__ bd, const int* __restrict__ flags,
                             const float* __restrict__ PX, float* __restrict__ Y) {
  __shared__ float As[16][68];
  __shared__ float Bs[16][68];
  const int M = Bb * LL2;  // 3138
  int f32 = flags[0];
  int m0 = blockIdx.x * 64, n0 = blockIdx.y * 64;
  int tid = threadIdx.x;
  int tx = tid & 15, ty = tid >> 4;
  int lm = tid >> 2, lk4 = (tid & 3) * 4;
  int am = m0 + lm; if (am >= M) am = M - 1;
  int b = am / LL2, q = am % LL2;
  float acc[4][4] = {};
  for (int k0 = 0; k0 < 4096; k0 += 16) {
    int hn = k0 >> 9;
    const float* ap = Outb + ((size_t)(b * NHh + hn) * LL2 + q) * 512 + (k0 & 511) + lk4;
    size_t bi = (size_t)(n0 + lm) * 4096 + k0 + lk4;
    #pragma unroll
    for (int c = 0; c < 4; ++c) As[lk4 + c][lm] = ap[c];
    #pragma unroll
    for (int c = 0; c < 4; ++c) Bs[lk4 + c][lm] = ldin(Wd, bi + c, f32);
    __syncthreads();
    mm_inner(As, Bs, tx, ty, acc);
    __syncthreads();
  }
  #pragma unroll
  for (int i = 0; i < 4; ++i) {
    int m = m0 + ty * 4 + i;
    if (m >= M) continue;
    float*       yp = Y  + (size_t)m * 512 + n0 + tx * 4;
    const float* px = PX + (size_t)m * 512 + n0 + tx * 4;
    #pragma unroll
    for (int j = 0; j < 4; ++j)
      yp[j] = acc[i][j] + ldin(bd, n0 + tx * 4 + j, f32) + px[j];
  }
}

// LayerNorm over 512, one block (256 thr) per row, f32 out (reference output dtype)
__global__ void ln_kernel(const float* __restrict__ Y, const void* __restrict__ gamma,
                          const void* __restrict__ beta, const int* __restrict__ flags,
                          float* __restrict__ Outp) {
  int row = blockIdx.x;
  const float* y = Y + (size_t)row * 512;
  __shared__ float red[256];
  int f32 = flags[0];
  int tid = threadIdx.x;
  float v0 = y[tid], v1 = y[tid + 256];
  red[tid] = v0 + v1; __syncthreads();
  for (int s = 128; s > 0; s >>= 1) { if (tid < s) red[tid] += red[tid + s]; __syncthreads(); }
  float mu = red[0] * (1.f / 512.f);
  __syncthreads();
  float d0 = v0 - mu, d1 = v1 - mu;
  red[tid] = d0 * d0 + d1 * d1; __syncthreads();
  for (int s = 128; s > 0; s >>= 1) { if (tid < s) red[tid] += red[tid + s]; __syncthreads(); }
  float rstd = rsqrtf(red[0] * (1.f / 512.f) + 1e-5f);
  float* o = Outp + (size_t)row * 512;
  o[tid]       = d0 * rstd * ldin(gamma, tid, f32)       + ldin(beta, tid, f32);
  o[tid + 256] = d1 * rstd * ldin(gamma, tid + 256, f32) + ldin(beta, tid + 256, f32);
}

// ---------------------------------------------------------------------------
extern "C" void kernel_launch(void* const* d_in, const int* in_sizes, int n_in,
                              void* d_out, int out_size, void* d_ws, size_t ws_size,
                              hipStream_t stream) {
  const void* x     = d_in[0];
  const void* Wq    = d_in[1];
  const void* bq    = d_in[2];
  const void* Wk    = d_in[3];
  const void* bk    = d_in[4];
  const void* Wv    = d_in[5];
  const void* bv    = d_in[6];
  const void* wpq   = d_in[7];
  const void* wpk   = d_in[8];
  const void* wpv   = d_in[9];
  const void* wpx   = d_in[10];
  const void* Wd    = d_in[11];
  const void* bd    = d_in[12];
  const void* gamma = d_in[13];
  const void* beta  = d_in[14];
  float* outp = (float*)d_out;   // reference output dtype = float32

  char* w = (char*)d_ws;
  auto alloc = [&](size_t bytes) { char* p = w; w += (bytes + 255) / 256 * 256; return p; };
  float* Qtmp = (float*)alloc((size_t)Ll * 512 * sizeof(float));         // 12.85 MB (per-g staging)
  float* PQg  = (float*)alloc((size_t)LL2 * 512 * sizeof(float));        // 3.2 MB
  float* PKg  = (float*)alloc((size_t)LL2 * 512 * sizeof(float));
  float* PVg  = (float*)alloc((size_t)LL2 * 512 * sizeof(float));
  float* embz = (float*)alloc((size_t)LL2 * 512 * sizeof(float));
  float* Lgg  = (float*)alloc((size_t)LL2 * LL2 * sizeof(float));        // 9.85 MB
  float* PX   = (float*)alloc((size_t)Bb * LL2 * 512 * sizeof(float));   // 6.4 MB
  float* Outb = (float*)alloc((size_t)Gg * LL2 * 512 * sizeof(float));   // 51.4 MB
  float* Y    = (float*)alloc((size_t)Bb * LL2 * 512 * sizeof(float));   // 6.4 MB
  int*   flags= (int*)  alloc(256);
  if ((size_t)(w - (char*)d_ws) > ws_size) return;  // fail w/o fault if ws too small

  dim3 blk(256);

  sniff_kernel<<<dim3(1), blk, 0, stream>>>(x, flags);
  emb_kernel<<<dim3(3138), blk, 0, stream>>>(embz);

  // PX = pool of x (both batches at once: g = row/Pp selects batch)
  pool_kernel<<<dim3(49, 8), blk, 0, stream>>>(x, 1, wpx, flags, PX, Bb * Pp);
  cls_copy<<<dim3(4), blk, 0, stream>>>(x, 1, flags, PX, Bb);

  // Per-(batch,head) pipeline
  for (int g = 0; g < Gg; ++g) {
    int b = g >> 3, h = g & 7;
    size_t xo = (size_t)b * Ll * 512;
    size_t wo = (size_t)h * 512 * 512;
    size_t bo = (size_t)h * 512;
    float* Outg = Outb + (size_t)g * LL2 * 512;

    proj_g_kernel<<<dim3(99, 8), blk, 0, stream>>>(x, xo, Wq, wo, bq, bo, flags, Qtmp);
    pool_kernel<<<dim3(25, 8), blk, 0, stream>>>(Qtmp, 0, wpq, flags, PQg, Pp);
    cls_copy<<<dim3(2), blk, 0, stream>>>(Qtmp, 0, flags, PQg, 1);

    proj_g_kernel<<<dim3(99, 8), blk, 0, stream>>>(x, xo, Wk, wo, bk, bo, flags, Qtmp);
    pool_kernel<<<dim3(25, 8), blk, 0, stream>>>(Qtmp, 0, wpk, flags, PKg, Pp);
    cls_copy<<<dim3(2), blk, 0, stream>>>(Qtmp, 0, flags, PKg, 1);

    proj_g_kernel<<<dim3(99, 8), blk, 0, stream>>>(x, xo, Wv, wo, bv, bo, flags, Qtmp);
    pool_kernel<<<dim3(25, 8), blk, 0, stream>>>(Qtmp, 0, wpv, flags, PVg, Pp);
    cls_copy<<<dim3(2), blk, 0, stream>>>(Qtmp, 0, flags, PVg, 1);

    pk_transform_g<<<dim3(3138), blk, 0, stream>>>(PKg, embz);
    logits_kernel<<<dim3(25, 25), blk, 0, stream>>>(PQg, PKg, Lgg);
    fixup_row0<<<dim3(LL2), dim3(64), 0, stream>>>(PQg, embz, Lgg);
    softmax_kernel<<<dim3(LL2), blk, 0, stream>>>(Lgg);
    av_kernel<<<dim3(25, 8), blk, 0, stream>>>(Lgg, PVg, PQg, Outg);
  }

  final_kernel<<<dim3(50, 8), blk, 0, stream>>>(Outb, Wd, bd, flags, PX, Y);
  ln_kernel<<<dim3(Bb * LL2), blk, 0, stream>>>(Y, gamma, beta, flags, outp);
}

// Round 5
// 2425.550 us; speedup vs baseline: 9.7899x; 9.7899x over previous
//
#include <hip/hip_runtime.h>
#include <hip/hip_bf16.h>
#include <cstdint>
#include <cstddef>

typedef __hip_bfloat16 bf16;
typedef __attribute__((ext_vector_type(8))) short short8;   // 8 bf16 in 4 VGPRs
typedef __attribute__((ext_vector_type(4))) float f32x4;
#define DEVI __device__ __forceinline__

constexpr int Bb = 2, Ll = 6273, Pp = 1568, LL2 = 1569, LP = 1600;
constexpr float QK_SCALE = 0.04419417382415922f;  // 512^-0.5

DEVI short f2bs(float f) {
  __hip_bfloat16 h = __float2bfloat16(f);
  return __builtin_bit_cast(short, h);
}
DEVI float bs2f(short s) {
  __hip_bfloat16 h = __builtin_bit_cast(__hip_bfloat16, s);
  return __bfloat162float(h);
}

// ---------------------------------------------------------------------------
// 64x64 MFMA tile core: 256 thr = 4 waves in 2x2; each wave 32x32 via 2x2
// mfma_f32_16x16x32_bf16 tiles. LDS tiles As[64][40], Bs[64][40] (bf16 bits).
// A[m][k] rows of C; B[n][k] cols of C (B = W rows, k contiguous).
// C/D layout per m89: col=lane&15, row=quad*4+reg.
// ---------------------------------------------------------------------------
constexpr int LDT = 40;

DEVI void mma_step(const short* As, const short* Bs, int lane, int wr, int wc,
                   f32x4& c00, f32x4& c01, f32x4& c10, f32x4& c11) {
  int m = lane & 15, quad = lane >> 4;
  const short* a = As + (wr * 32 + m) * LDT + quad * 8;
  const short* b = Bs + (wc * 32 + m) * LDT + quad * 8;
  short8 a0 = *(const short8*)a;
  short8 a1 = *(const short8*)(a + 16 * LDT);
  short8 b0 = *(const short8*)b;
  short8 b1 = *(const short8*)(b + 16 * LDT);
  c00 = __builtin_amdgcn_mfma_f32_16x16x32_bf16(a0, b0, c00, 0, 0, 0);
  c01 = __builtin_amdgcn_mfma_f32_16x16x32_bf16(a0, b1, c01, 0, 0, 0);
  c10 = __builtin_amdgcn_mfma_f32_16x16x32_bf16(a1, b0, c10, 0, 0, 0);
  c11 = __builtin_amdgcn_mfma_f32_16x16x32_bf16(a1, b1, c11, 0, 0, 0);
}

// ---------------------------------------------------------------------------
// Positional embedding (zero row 0 and rows >= 1569). f32 [1600][512].
// ---------------------------------------------------------------------------
__global__ void emb_kernel(float* __restrict__ embz) {
  int idx = blockIdx.x * 256 + threadIdx.x;
  if (idx >= LP * 512) return;
  int p = idx >> 9, d = idx & 511;
  float v = 0.f;
  if (p > 0 && p < LL2) {
    int pb = p - 1;
    int t = pb / 196, r = pb % 196;
    int h = r / 14, ww = r % 14;
    int pos, j, half;
    if (d < 170)      { pos = t;  j = d;       half = 85; }
    else if (d < 340) { pos = h;  j = d - 170; half = 85; }
    else              { pos = ww; j = d - 340; half = 86; }
    int jj = (j < half) ? j : (j - half);
    float omega = powf(10000.f, -(float)jj / (float)half);
    float ang = (float)pos * omega;
    v = (j < half) ? sinf(ang) : cosf(ang);
  }
  embz[idx] = v;
}

// wpxT[n][tap*512+k] = bf16(wpx[n*2048 + k*4 + tap])
__global__ void wpxt_kernel(const float* __restrict__ wpx, short* __restrict__ wpxT) {
  int idx = blockIdx.x * 256 + threadIdx.x;
  if (idx >= 512 * 2048) return;
  int n = idx >> 11, rem = idx & 2047, tap = rem >> 9, k = rem & 511;
  wpxT[idx] = f2bs(wpx[n * 2048 + k * 4 + tap]);
}

// WT[h][k][i] = bf16(W[(h*512+i)*512 + k])  (LDS tile transpose)
__global__ void tr_w_kernel(const float* __restrict__ W, short* __restrict__ WT) {
  __shared__ float Ws[64][65];
  int i0 = blockIdx.x * 64, k0 = blockIdx.y * 64, h = blockIdx.z;
  int tid = threadIdx.x;
  int r = tid >> 2, c0 = (tid & 3) * 16;
  const float* src = W + ((size_t)(h * 512 + i0 + r)) * 512 + k0 + c0;
  #pragma unroll
  for (int j = 0; j < 16; ++j) Ws[r][c0 + j] = src[j];
  __syncthreads();
  short* dst = WT + ((size_t)(h * 512 + k0 + r)) * 512 + i0 + c0;
  #pragma unroll
  for (int j = 0; j < 16; ++j) dst[j] = f2bs(Ws[c0 + j][r]);
}

// Weff[ch][n][tap*512+k] = sum_i wp[n,i,tap] * W[(h*512+i)][k]  (via WT)
__global__ void weff_kernel(const float* __restrict__ wp, const short* __restrict__ WT,
                            int h0, short* __restrict__ Weff) {
  __shared__ short As[64 * LDT];
  __shared__ short Bs[64 * LDT];
  int n0 = blockIdx.x * 64, kO = blockIdx.y * 64;
  int ch = blockIdx.z >> 2, tap = blockIdx.z & 3;
  int h = h0 + ch;
  int tid = threadIdx.x, lane = tid & 63, w = tid >> 6, wr = w >> 1, wc = w & 1;
  int sr = tid >> 2, sc = (tid & 3) * 8;
  f32x4 acc[2][2] = {};
  for (int i0 = 0; i0 < 512; i0 += 32) {
    const float* a = wp + (size_t)(n0 + sr) * 2048 + (size_t)(i0 + sc) * 4 + tap;
    short8 av;
    #pragma unroll
    for (int j = 0; j < 8; ++j) av[j] = f2bs(a[j * 4]);
    *(short8*)(As + sr * LDT + sc) = av;
    const short* bsrc = WT + ((size_t)(h * 512 + kO + sr)) * 512 + i0 + sc;
    *(short8*)(Bs + sr * LDT + sc) = *(const short8*)bsrc;
    __syncthreads();
    mma_step(As, Bs, lane, wr, wc, acc[0][0], acc[0][1], acc[1][0], acc[1][1]);
    __syncthreads();
  }
  int m = lane & 15, quad = lane >> 4;
  #pragma unroll
  for (int ri = 0; ri < 2; ++ri)
    #pragma unroll
    for (int ci = 0; ci < 2; ++ci)
      #pragma unroll
      for (int e = 0; e < 4; ++e) {
        int n = n0 + wr * 32 + ri * 16 + quad * 4 + e;
        int k = kO + wc * 32 + ci * 16 + m;
        Weff[((size_t)(ch * 512 + n)) * 2048 + tap * 512 + k] = f2bs(acc[ri][ci][e]);
      }
}

// beff[ch][n] = sum_i bias[(h0+ch)*512+i] * sum_tap wp[n,i,tap]
__global__ void beff_kernel(const float* __restrict__ bias, const float* __restrict__ wp,
                            int h0, float* __restrict__ beff) {
  int ch = blockIdx.x, tid = threadIdx.x;
  for (int n = tid; n < 512; n += 256) {
    float s = 0.f;
    for (int i = 0; i < 512; ++i) {
      float bi = bias[(h0 + ch) * 512 + i];
      const float* w4 = wp + (size_t)n * 2048 + i * 4;
      s += bi * (w4[0] + w4[1] + w4[2] + w4[3]);
    }
    beff[ch * 512 + n] = s;
  }
}

// ---------------------------------------------------------------------------
// Pooled GEMM: out[cg][token][n] = sum_{tap,k} x[b][lrow][k] * Weff[ch][n][tap*512+k]
// mode 0=Q (+beff), 1=K (+beff, *scale + embz, fold), 2=V (+beff, transposed store),
// 3=PX (no bias, cg = b)
// ---------------------------------------------------------------------------
__global__ void pool_mfma(const float* __restrict__ x, const short* __restrict__ Wf,
                          const float* __restrict__ beff, const float* __restrict__ embz,
                          short* __restrict__ Out, int mode, int CH) {
  __shared__ short As[64 * LDT];
  __shared__ short Bs[64 * LDT];
  int mt = blockIdx.x % 25, cg = blockIdx.x / 25;
  int n0 = blockIdx.y * 64;
  int b  = (mode == 3) ? cg : cg / CH;
  int ch = (mode == 3) ? 0  : cg % CH;
  int tid = threadIdx.x, lane = tid & 63, w = tid >> 6, wr = w >> 1, wc = w & 1;
  int sr = tid >> 2, sc = (tid & 3) * 8;
  int mloc = mt * 64 + sr;
  int pb = mloc < Pp ? mloc : (Pp - 1);
  int t3 = pb / 196, rm = pb % 196, h2 = rm / 14, w2 = rm % 14;
  int l0 = 1 + t3 * 784 + h2 * 56 + w2 * 2;
  const float* xb = x + (size_t)b * Ll * 512;
  f32x4 acc[2][2] = {};
  for (int kq = 0; kq < 2048; kq += 32) {
    int tap = kq >> 9;
    int lrow = l0 + (tap >> 1) * 28 + (tap & 1);
    const float* a = xb + (size_t)lrow * 512 + (kq & 511) + sc;
    float4 v0 = *(const float4*)a;
    float4 v1 = *(const float4*)(a + 4);
    short8 av = { f2bs(v0.x), f2bs(v0.y), f2bs(v0.z), f2bs(v0.w),
                  f2bs(v1.x), f2bs(v1.y), f2bs(v1.z), f2bs(v1.w) };
    *(short8*)(As + sr * LDT + sc) = av;
    const short* bsrc = Wf + ((size_t)(ch * 512 + n0 + sr)) * 2048 + kq + sc;
    *(short8*)(Bs + sr * LDT + sc) = *(const short8*)bsrc;
    __syncthreads();
    mma_step(As, Bs, lane, wr, wc, acc[0][0], acc[0][1], acc[1][0], acc[1][1]);
    __syncthreads();
  }
  int m = lane & 15, quad = lane >> 4;
  #pragma unroll
  for (int ri = 0; ri < 2; ++ri)
    #pragma unroll
    for (int ci = 0; ci < 2; ++ci)
      #pragma unroll
      for (int e = 0; e < 4; ++e) {
        int mrow = mt * 64 + wr * 32 + ri * 16 + quad * 4 + e;
        int tok = mrow + 1; if (tok > LP - 1) tok = LP - 1;
        int n = n0 + wc * 32 + ci * 16 + m;
        float v = acc[ri][ci][e];
        if (mode == 3) {
          Out[((size_t)b * LP + tok) * 512 + n] = f2bs(v);
        } else {
          v += beff[ch * 512 + n];
          if (mode == 1) v = v * QK_SCALE + embz[(size_t)tok * 512 + n];
          if (mode == 2) Out[((size_t)cg * 512 + n) * LP + tok] = f2bs(v);
          else           Out[((size_t)cg * LP + tok) * 512 + n] = f2bs(v);
        }
      }
}

// cls token (row 0) for PQ / PKf(scaled; emb row0=0) / PVt. block=512 thr.
__global__ void cls_kernel(const float* __restrict__ x,
                           const float* __restrict__ Wq, const float* __restrict__ bq,
                           const float* __restrict__ Wk, const float* __restrict__ bk,
                           const float* __restrict__ Wv, const float* __restrict__ bv,
                           int h0, int CH,
                           short* __restrict__ PQ, short* __restrict__ PKf,
                           short* __restrict__ PVt) {
  int cg = blockIdx.x;
  int b = cg / CH, h = h0 + cg % CH;
  int n = threadIdx.x;
  const float* xr = x + (size_t)b * Ll * 512;
  const float* wq = Wq + ((size_t)(h * 512 + n)) * 512;
  const float* wk = Wk + ((size_t)(h * 512 + n)) * 512;
  const float* wv = Wv + ((size_t)(h * 512 + n)) * 512;
  float sq = bq[h * 512 + n], sk = bk[h * 512 + n], sv = bv[h * 512 + n];
  for (int k = 0; k < 512; ++k) {
    float xv = xr[k];
    sq += xv * wq[k]; sk += xv * wk[k]; sv += xv * wv[k];
  }
  PQ[((size_t)cg * LP) * 512 + n] = f2bs(sq);
  PKf[((size_t)cg * LP) * 512 + n] = f2bs(sk * QK_SCALE);
  PVt[((size_t)cg * 512 + n) * LP] = f2bs(sv);
}

// PX cls row: PX[b][0][:] = x[b][0][:]
__global__ void pxcls_kernel(const float* __restrict__ x, short* __restrict__ PX) {
  int b = blockIdx.x, n = threadIdx.x;
  PX[(size_t)b * LP * 512 + n] = f2bs(x[(size_t)b * Ll * 512 + n]);
}

// cfx[cg][kt] = dot(PQ[cg,0,:], embz[kt,:])  (row-0 fold correction)
__global__ void cfix_kernel(const short* __restrict__ PQ, const float* __restrict__ embz,
                            float* __restrict__ cfx) {
  int cg = blockIdx.y;
  int wv = threadIdx.x >> 6, lane = threadIdx.x & 63;
  int kt = blockIdx.x * 4 + wv;
  if (kt >= LP) return;
  int ktc = kt < LL2 ? kt : (LL2 - 1);
  const short* q0 = PQ + (size_t)cg * LP * 512;
  const float* e = embz + (size_t)ktc * 512;
  float s = 0.f;
  #pragma unroll
  for (int j = 0; j < 8; ++j) {
    int d = lane * 8 + j;
    s += bs2f(q0[d]) * e[d];
  }
  #pragma unroll
  for (int off = 32; off; off >>= 1) s += __shfl_down(s, off, 64);
  if (lane == 0) cfx[(size_t)cg * LP + kt] = s;
}

// logits[cg][q][kt] (f32) = PQ . PKf ; row 0 -= cfx
__global__ void logits_mfma(const short* __restrict__ PQ, const short* __restrict__ PKf,
                            const float* __restrict__ cfx, float* __restrict__ Lg) {
  __shared__ short As[64 * LDT];
  __shared__ short Bs[64 * LDT];
  int q0 = blockIdx.x * 64, k0 = blockIdx.y * 64, cg = blockIdx.z;
  int tid = threadIdx.x, lane = tid & 63, w = tid >> 6, wr = w >> 1, wc = w & 1;
  int sr = tid >> 2, sc = (tid & 3) * 8;
  const short* Aq = PQ + (size_t)cg * LP * 512;
  const short* Bk = PKf + (size_t)cg * LP * 512;
  f32x4 acc[2][2] = {};
  for (int kd = 0; kd < 512; kd += 32) {
    *(short8*)(As + sr * LDT + sc) = *(const short8*)(Aq + (size_t)(q0 + sr) * 512 + kd + sc);
    *(short8*)(Bs + sr * LDT + sc) = *(const short8*)(Bk + (size_t)(k0 + sr) * 512 + kd + sc);
    __syncthreads();
    mma_step(As, Bs, lane, wr, wc, acc[0][0], acc[0][1], acc[1][0], acc[1][1]);
    __syncthreads();
  }
  int m = lane & 15, quad = lane >> 4;
  float* lg = Lg + (size_t)cg * LP * LP;
  const float* cf = cfx + (size_t)cg * LP;
  #pragma unroll
  for (int ri = 0; ri < 2; ++ri)
    #pragma unroll
    for (int ci = 0; ci < 2; ++ci)
      #pragma unroll
      for (int e = 0; e < 4; ++e) {
        int q = q0 + wr * 32 + ri * 16 + quad * 4 + e;
        int kt = k0 + wc * 32 + ci * 16 + m;
        float v = acc[ri][ci][e];
        if (q == 0) v -= cf[kt];
        lg[(size_t)q * LP + kt] = v;
      }
}

// softmax row (f32 in) -> bf16 attn written in place over the row start
__global__ void softmax_kernel(float* __restrict__ Lg) {
  int q = blockIdx.x, cg = blockIdx.y;
  float* p = Lg + ((size_t)cg * LP + q) * LP;
  __shared__ float buf[LP];
  __shared__ float red[256];
  int tid = threadIdx.x;
  float mx = -1e30f;
  for (int j = tid; j < LL2; j += 256) { float v = p[j]; buf[j] = v; mx = fmaxf(mx, v); }
  red[tid] = mx; __syncthreads();
  for (int s = 128; s; s >>= 1) { if (tid < s) red[tid] = fmaxf(red[tid], red[tid + s]); __syncthreads(); }
  mx = red[0]; __syncthreads();
  float sum = 0.f;
  for (int j = tid; j < LL2; j += 256) { float e = __expf(buf[j] - mx); buf[j] = e; sum += e; }
  red[tid] = sum; __syncthreads();
  for (int s = 128; s; s >>= 1) { if (tid < s) red[tid] += red[tid + s]; __syncthreads(); }
  float inv = 1.f / red[0];
  short* o = (short*)p;
  for (int j = tid; j < LL2; j += 256) o[j] = f2bs(buf[j] * inv);
  for (int j = LL2 + tid; j < LP; j += 256) o[j] = 0;
}

// Outb[g][q][n] = attn[q,:] @ PVt + (q==0?1:2)*PQ[q][n]
__global__ void av_mfma(const float* __restrict__ Lg, const short* __restrict__ PVt,
                        const short* __restrict__ PQ, short* __restrict__ Outb,
                        int h0, int CH) {
  __shared__ short As[64 * LDT];
  __shared__ short Bs[64 * LDT];
  int q0 = blockIdx.x * 64, n0 = blockIdx.y * 64, cg = blockIdx.z;
  int b = cg / CH, gg = b * 8 + h0 + cg % CH;
  int tid = threadIdx.x, lane = tid & 63, w = tid >> 6, wr = w >> 1, wc = w & 1;
  int sr = tid >> 2, sc = (tid & 3) * 8;
  const short* Aat = (const short*)(Lg + (size_t)cg * LP * LP);  // bf16 view, stride 2*LP
  const short* Bv = PVt + (size_t)cg * 512 * LP;
  f32x4 acc[2][2] = {};
  for (int kt = 0; kt < LP; kt += 32) {
    *(short8*)(As + sr * LDT + sc) = *(const short8*)(Aat + (size_t)(q0 + sr) * (2 * LP) + kt + sc);
    *(short8*)(Bs + sr * LDT + sc) = *(const short8*)(Bv + (size_t)(n0 + sr) * LP + kt + sc);
    __syncthreads();
    mma_step(As, Bs, lane, wr, wc, acc[0][0], acc[0][1], acc[1][0], acc[1][1]);
    __syncthreads();
  }
  int m = lane & 15, quad = lane >> 4;
  #pragma unroll
  for (int ri = 0; ri < 2; ++ri)
    #pragma unroll
    for (int ci = 0; ci < 2; ++ci)
      #pragma unroll
      for (int e = 0; e < 4; ++e) {
        int q = q0 + wr * 32 + ri * 16 + quad * 4 + e;
        if (q >= LL2) continue;
        int n = n0 + wc * 32 + ci * 16 + m;
        float res = bs2f(PQ[((size_t)cg * LP + q) * 512 + n]);
        float v = acc[ri][ci][e] + (q == 0 ? 1.f : 2.f) * res;
        Outb[((size_t)gg * LP + q) * 512 + n] = f2bs(v);
      }
}

// Y[b,q,dm] = stacked @ Wd^T + bd + PX
__global__ void final_mfma(const short* __restrict__ Outb, const float* __restrict__ Wd,
                           const float* __restrict__ bd, const short* __restrict__ PX,
                           float* __restrict__ Y) {
  __shared__ short As[64 * LDT];
  __shared__ short Bs[64 * LDT];
  int mt = blockIdx.x % 25, b = blockIdx.x / 25;
  int n0 = blockIdx.y * 64;
  int tid = threadIdx.x, lane = tid & 63, w = tid >> 6, wr = w >> 1, wc = w & 1;
  int sr = tid >> 2, sc = (tid & 3) * 8;
  int qrow = mt * 64 + sr; if (qrow > LL2 - 1) qrow = LL2 - 1;
  f32x4 acc[2][2] = {};
  for (int kq = 0; kq < 4096; kq += 32) {
    int hh = kq >> 9;
    const short* a = Outb + ((size_t)(b * 8 + hh) * LP + qrow) * 512 + (kq & 511) + sc;
    *(short8*)(As + sr * LDT + sc) = *(const short8*)a;
    const float* bw = Wd + (size_t)(n0 + sr) * 4096 + kq + sc;
    float4 v0 = *(const float4*)bw;
    float4 v1 = *(const float4*)(bw + 4);
    short8 bv8 = { f2bs(v0.x), f2bs(v0.y), f2bs(v0.z), f2bs(v0.w),
                   f2bs(v1.x), f2bs(v1.y), f2bs(v1.z), f2bs(v1.w) };
    *(short8*)(Bs + sr * LDT + sc) = bv8;
    __syncthreads();
    mma_step(As, Bs, lane, wr, wc, acc[0][0], acc[0][1], acc[1][0], acc[1][1]);
    __syncthreads();
  }
  int m = lane & 15, quad = lane >> 4;
  #pragma unroll
  for (int ri = 0; ri < 2; ++ri)
    #pragma unroll
    for (int ci = 0; ci < 2; ++ci)
      #pragma unroll
      for (int e = 0; e < 4; ++e) {
        int q = mt * 64 + wr * 32 + ri * 16 + quad * 4 + e;
        if (q >= LL2) continue;
        int dm = n0 + wc * 32 + ci * 16 + m;
        float v = acc[ri][ci][e] + bd[dm] + bs2f(PX[((size_t)b * LP + q) * 512 + dm]);
        Y[((size_t)(b * LL2 + q)) * 512 + dm] = v;
      }
}

// LayerNorm over 512, f32 in/out
__global__ void ln_kernel(const float* __restrict__ Y, const float* __restrict__ gamma,
                          const float* __restrict__ beta, float* __restrict__ Outp) {
  int row = blockIdx.x;
  const float* y = Y + (size_t)row * 512;
  __shared__ float red[256];
  int tid = threadIdx.x;
  float v0 = y[tid], v1 = y[tid + 256];
  red[tid] = v0 + v1; __syncthreads();
  for (int s = 128; s; s >>= 1) { if (tid < s) red[tid] += red[tid + s]; __syncthreads(); }
  float mu = red[0] * (1.f / 512.f);
  __syncthreads();
  float d0 = v0 - mu, d1 = v1 - mu;
  red[tid] = d0 * d0 + d1 * d1; __syncthreads();
  for (int s = 128; s; s >>= 1) { if (tid < s) red[tid] += red[tid + s]; __syncthreads(); }
  float rstd = rsqrtf(red[0] * (1.f / 512.f) + 1e-5f);
  float* o = Outp + (size_t)row * 512;
  o[tid]       = d0 * rstd * gamma[tid]       + beta[tid];
  o[tid + 256] = d1 * rstd * gamma[tid + 256] + beta[tid + 256];
}

// ---------------------------------------------------------------------------
extern "C" void kernel_launch(void* const* d_in, const int* in_sizes, int n_in,
                              void* d_out, int out_size, void* d_ws, size_t ws_size,
                              hipStream_t stream) {
  const float* x     = (const float*)d_in[0];
  const float* Wq    = (const float*)d_in[1];
  const float* bq    = (const float*)d_in[2];
  const float* Wk    = (const float*)d_in[3];
  const float* bk    = (const float*)d_in[4];
  const float* Wv    = (const float*)d_in[5];
  const float* bv    = (const float*)d_in[6];
  const float* wpq   = (const float*)d_in[7];
  const float* wpk   = (const float*)d_in[8];
  const float* wpv   = (const float*)d_in[9];
  const float* wpx   = (const float*)d_in[10];
  const float* Wd    = (const float*)d_in[11];
  const float* bd    = (const float*)d_in[12];
  const float* gamma = (const float*)d_in[13];
  const float* beta  = (const float*)d_in[14];
  float* outp = (float*)d_out;

  auto rnd = [](size_t b) { return (b + 255) / 256 * 256; };
  const size_t persist =
      rnd((size_t)LP * 512 * 4) + rnd((size_t)512 * 2048 * 2) + 3 * rnd((size_t)8 * 512 * 512 * 2) +
      rnd((size_t)16 * LP * 512 * 2) + rnd((size_t)2 * LP * 512 * 2) + rnd((size_t)2 * LL2 * 512 * 4);
  auto chunkBytes = [&](int CH) {
    return rnd((size_t)CH * 512 * 2048 * 2) + rnd((size_t)CH * 512 * 4) +
           3 * rnd((size_t)2 * CH * LP * 512 * 2) + rnd((size_t)2 * CH * LP * 4) +
           rnd((size_t)2 * CH * LP * LP * 4);
  };
  int CH = 8;
  while (CH > 1 && persist + chunkBytes(CH) + 65536 > ws_size) CH >>= 1;
  if (persist + chunkBytes(CH) + 65536 > ws_size) return;  // cannot fit (ws < ~87MB)
  int nc = 8 / CH;

  char* w = (char*)d_ws;
  auto alloc = [&](size_t bytes) { char* p = w; w += (bytes + 255) / 256 * 256; return p; };
  float* embz = (float*)alloc((size_t)LP * 512 * 4);
  short* wpxT = (short*)alloc((size_t)512 * 2048 * 2);
  short* WqT  = (short*)alloc((size_t)8 * 512 * 512 * 2);
  short* WkT  = (short*)alloc((size_t)8 * 512 * 512 * 2);
  short* WvT  = (short*)alloc((size_t)8 * 512 * 512 * 2);
  short* Outb = (short*)alloc((size_t)16 * LP * 512 * 2);
  short* PX   = (short*)alloc((size_t)2 * LP * 512 * 2);
  float* Y    = (float*)alloc((size_t)2 * LL2 * 512 * 4);
  short* Weff = (short*)alloc((size_t)CH * 512 * 2048 * 2);
  float* beff = (float*)alloc((size_t)CH * 512 * 4);
  short* PQ   = (short*)alloc((size_t)2 * CH * LP * 512 * 2);
  short* PKf  = (short*)alloc((size_t)2 * CH * LP * 512 * 2);
  short* PVt  = (short*)alloc((size_t)2 * CH * LP * 512 * 2);
  float* cfx  = (float*)alloc((size_t)2 * CH * LP * 4);
  float* Lg   = (float*)alloc((size_t)2 * CH * LP * LP * 4);

  dim3 blk(256);
  emb_kernel<<<dim3((LP * 512 + 255) / 256), blk, 0, stream>>>(embz);
  wpxt_kernel<<<dim3((512 * 2048 + 255) / 256), blk, 0, stream>>>(wpx, wpxT);
  tr_w_kernel<<<dim3(8, 8, 8), blk, 0, stream>>>(Wq, WqT);
  tr_w_kernel<<<dim3(8, 8, 8), blk, 0, stream>>>(Wk, WkT);
  tr_w_kernel<<<dim3(8, 8, 8), blk, 0, stream>>>(Wv, WvT);
  pool_mfma<<<dim3(25 * 2, 8), blk, 0, stream>>>(x, wpxT, beff, embz, PX, 3, CH);
  pxcls_kernel<<<dim3(2), dim3(512), 0, stream>>>(x, PX);

  for (int c = 0; c < nc; ++c) {
    int h0 = c * CH;
    // Q
    weff_kernel<<<dim3(8, 8, 4 * CH), blk, 0, stream>>>(wpq, WqT, h0, Weff);
    beff_kernel<<<dim3(CH), blk, 0, stream>>>(bq, wpq, h0, beff);
    pool_mfma<<<dim3(25 * 2 * CH, 8), blk, 0, stream>>>(x, Weff, beff, embz, PQ, 0, CH);
    // K (folded: *scale + emb)
    weff_kernel<<<dim3(8, 8, 4 * CH), blk, 0, stream>>>(wpk, WkT, h0, Weff);
    beff_kernel<<<dim3(CH), blk, 0, stream>>>(bk, wpk, h0, beff);
    pool_mfma<<<dim3(25 * 2 * CH, 8), blk, 0, stream>>>(x, Weff, beff, embz, PKf, 1, CH);
    // V (transposed store)
    weff_kernel<<<dim3(8, 8, 4 * CH), blk, 0, stream>>>(wpv, WvT, h0, Weff);
    beff_kernel<<<dim3(CH), blk, 0, stream>>>(bv, wpv, h0, beff);
    pool_mfma<<<dim3(25 * 2 * CH, 8), blk, 0, stream>>>(x, Weff, beff, embz, PVt, 2, CH);
    // cls rows, fold fixup, attention
    cls_kernel<<<dim3(2 * CH), dim3(512), 0, stream>>>(x, Wq, bq, Wk, bk, Wv, bv,
                                                       h0, CH, PQ, PKf, PVt);
    cfix_kernel<<<dim3(400, 2 * CH), blk, 0, stream>>>(PQ, embz, cfx);
    logits_mfma<<<dim3(25, 25, 2 * CH), blk, 0, stream>>>(PQ, PKf, cfx, Lg);
    softmax_kernel<<<dim3(LL2, 2 * CH), blk, 0, stream>>>(Lg);
    av_mfma<<<dim3(25, 8, 2 * CH), blk, 0, stream>>>(Lg, PVt, PQ, Outb, h0, CH);
  }

  final_mfma<<<dim3(50, 8), blk, 0, stream>>>(Outb, Wd, bd, PX, Y);
  ln_kernel<<<dim3(Bb * LL2), blk, 0, stream>>>(Y, gamma, beta, outp);
}

// Round 6
// 1662.767 us; speedup vs baseline: 14.2810x; 1.4587x over previous
//
#include <hip/hip_runtime.h>
#include <hip/hip_bf16.h>
#include <cstdint>
#include <cstddef>

typedef __hip_bfloat16 bf16;
typedef __attribute__((ext_vector_type(8))) short short8;   // 8 bf16 in 4 VGPRs
typedef __attribute__((ext_vector_type(4))) short short4v;
typedef __attribute__((ext_vector_type(4))) float f32x4;
#define DEVI __device__ __forceinline__

constexpr int Bb = 2, Ll = 6273, Pp = 1568, LL2 = 1569, LP = 1600;
constexpr float QK_SCALE = 0.04419417382415922f;  // 512^-0.5

DEVI short f2bs(float f) {
  __hip_bfloat16 h = __float2bfloat16(f);
  return __builtin_bit_cast(short, h);
}
DEVI float bs2f(short s) {
  __hip_bfloat16 h = __builtin_bit_cast(__hip_bfloat16, s);
  return __bfloat162float(h);
}

// ---------------------------------------------------------------------------
// 64x64 MFMA tile core: 256 thr = 4 waves in 2x2; each wave 32x32 via 2x2
// mfma_f32_16x16x32_bf16. LDS As[64][40], Bs[64][40]. C/D: col=lane&15,
// row=quad*4+e (m89-verified).
// ---------------------------------------------------------------------------
constexpr int LDT = 40;

DEVI void mma_step(const short* As, const short* Bs, int lane, int wr, int wc,
                   f32x4& c00, f32x4& c01, f32x4& c10, f32x4& c11) {
  int m = lane & 15, quad = lane >> 4;
  const short* a = As + (wr * 32 + m) * LDT + quad * 8;
  const short* b = Bs + (wc * 32 + m) * LDT + quad * 8;
  short8 a0 = *(const short8*)a;
  short8 a1 = *(const short8*)(a + 16 * LDT);
  short8 b0 = *(const short8*)b;
  short8 b1 = *(const short8*)(b + 16 * LDT);
  c00 = __builtin_amdgcn_mfma_f32_16x16x32_bf16(a0, b0, c00, 0, 0, 0);
  c01 = __builtin_amdgcn_mfma_f32_16x16x32_bf16(a0, b1, c01, 0, 0, 0);
  c10 = __builtin_amdgcn_mfma_f32_16x16x32_bf16(a1, b0, c10, 0, 0, 0);
  c11 = __builtin_amdgcn_mfma_f32_16x16x32_bf16(a1, b1, c11, 0, 0, 0);
}

// ---------------------------------------------------------------------------
__global__ void emb_kernel(float* __restrict__ embz) {
  int idx = blockIdx.x * 256 + threadIdx.x;
  if (idx >= LP * 512) return;
  int p = idx >> 9, d = idx & 511;
  float v = 0.f;
  if (p > 0 && p < LL2) {
    int pb = p - 1;
    int t = pb / 196, r = pb % 196;
    int h = r / 14, ww = r % 14;
    int pos, j, half;
    if (d < 170)      { pos = t;  j = d;       half = 85; }
    else if (d < 340) { pos = h;  j = d - 170; half = 85; }
    else              { pos = ww; j = d - 340; half = 86; }
    int jj = (j < half) ? j : (j - half);
    float omega = powf(10000.f, -(float)jj / (float)half);
    float ang = (float)pos * omega;
    v = (j < half) ? sinf(ang) : cosf(ang);
  }
  embz[idx] = v;
}

// f32 -> bf16 bulk convert, 4 elements/thread
__global__ void cvt_kernel(const float* __restrict__ src, short* __restrict__ dst, int n4) {
  int idx = blockIdx.x * 256 + threadIdx.x;
  if (idx >= n4) return;
  float4 v = *(const float4*)(src + (size_t)idx * 4);
  short4v o = { f2bs(v.x), f2bs(v.y), f2bs(v.z), f2bs(v.w) };
  *(short4v*)(dst + (size_t)idx * 4) = o;
}

// wpxT[n][tap*512+k] = bf16(wpx[n*2048 + k*4 + tap])
__global__ void wpxt_kernel(const float* __restrict__ wpx, short* __restrict__ wpxT) {
  int idx = blockIdx.x * 256 + threadIdx.x;
  if (idx >= 512 * 2048) return;
  int n = idx >> 11, rem = idx & 2047, tap = rem >> 9, k = rem & 511;
  wpxT[idx] = f2bs(wpx[n * 2048 + k * 4 + tap]);
}

// WT[h][k][i] = bf16(W[(h*512+i)*512 + k])
__global__ void tr_w_kernel(const float* __restrict__ W, short* __restrict__ WT) {
  __shared__ float Ws[64][65];
  int i0 = blockIdx.x * 64, k0 = blockIdx.y * 64, h = blockIdx.z;
  int tid = threadIdx.x;
  int r = tid >> 2, c0 = (tid & 3) * 16;
  const float* src = W + ((size_t)(h * 512 + i0 + r)) * 512 + k0 + c0;
  #pragma unroll
  for (int j = 0; j < 16; ++j) Ws[r][c0 + j] = src[j];
  __syncthreads();
  short* dst = WT + ((size_t)(h * 512 + k0 + r)) * 512 + i0 + c0;
  #pragma unroll
  for (int j = 0; j < 16; ++j) dst[j] = f2bs(Ws[c0 + j][r]);
}

// Weff_all[(mat*CH+ch)][n][tap*512+k] = sum_i wp_mat[n,i,tap] * W_mat[h0+ch][i][k]
__global__ void weff_fused(const float* __restrict__ wpq, const float* __restrict__ wpk,
                           const float* __restrict__ wpv,
                           const short* __restrict__ WqT, const short* __restrict__ WkT,
                           const short* __restrict__ WvT,
                           int h0, int CH, short* __restrict__ Weff) {
  __shared__ short As[64 * LDT];
  __shared__ short Bs[64 * LDT];
  int n0 = blockIdx.x * 64, kO = blockIdx.y * 64;
  int z = blockIdx.z;
  int mat = z / (4 * CH), rem = z % (4 * CH);
  int ch = rem >> 2, tap = rem & 3;
  const float* wp = mat == 0 ? wpq : (mat == 1 ? wpk : wpv);
  const short* WT = mat == 0 ? WqT : (mat == 1 ? WkT : WvT);
  int h = h0 + ch;
  int tid = threadIdx.x, lane = tid & 63, w = tid >> 6, wr = w >> 1, wc = w & 1;
  int sr = tid >> 2, sc = (tid & 3) * 8;
  f32x4 acc[2][2] = {};
  for (int i0 = 0; i0 < 512; i0 += 32) {
    const float* a = wp + (size_t)(n0 + sr) * 2048 + (size_t)(i0 + sc) * 4 + tap;
    short8 av;
    #pragma unroll
    for (int j = 0; j < 8; ++j) av[j] = f2bs(a[j * 4]);
    *(short8*)(As + sr * LDT + sc) = av;
    const short* bsrc = WT + ((size_t)(h * 512 + kO + sr)) * 512 + i0 + sc;
    *(short8*)(Bs + sr * LDT + sc) = *(const short8*)bsrc;
    __syncthreads();
    mma_step(As, Bs, lane, wr, wc, acc[0][0], acc[0][1], acc[1][0], acc[1][1]);
    __syncthreads();
  }
  int m = lane & 15, quad = lane >> 4;
  #pragma unroll
  for (int ri = 0; ri < 2; ++ri)
    #pragma unroll
    for (int ci = 0; ci < 2; ++ci)
      #pragma unroll
      for (int e = 0; e < 4; ++e) {
        int n = n0 + wr * 32 + ri * 16 + quad * 4 + e;
        int k = kO + wc * 32 + ci * 16 + m;
        Weff[((size_t)((mat * CH + ch) * 512 + n)) * 2048 + tap * 512 + k] = f2bs(acc[ri][ci][e]);
      }
}

// beff_all[(mat*CH+ch)][n] = sum_i bias[h][i] * sum_tap wp[n,i,tap]
__global__ void beff_fused(const float* __restrict__ bq, const float* __restrict__ bk,
                           const float* __restrict__ bv,
                           const float* __restrict__ wpq, const float* __restrict__ wpk,
                           const float* __restrict__ wpv,
                           int h0, int CH, float* __restrict__ beff) {
  int mat = blockIdx.x, ch = blockIdx.y, tid = threadIdx.x;
  const float* bias = mat == 0 ? bq : (mat == 1 ? bk : bv);
  const float* wp = mat == 0 ? wpq : (mat == 1 ? wpk : wpv);
  for (int n = tid; n < 512; n += 256) {
    float s = 0.f;
    for (int i = 0; i < 512; ++i) {
      float bi = bias[(h0 + ch) * 512 + i];
      const float* w4 = wp + (size_t)n * 2048 + i * 4;
      s += bi * (w4[0] + w4[1] + w4[2] + w4[3]);
    }
    beff[(mat * CH + ch) * 512 + n] = s;
  }
}

// ---------------------------------------------------------------------------
// Fused pooled GEMM for Q/K/V: y -> (mat, n-tile). x pre-converted bf16.
// mat 0=Q (+beff), 1=K (+beff, *scale+embz), 2=V (+beff, transposed store)
// ---------------------------------------------------------------------------
__global__ void pool_fused(const short* __restrict__ xbf, const short* __restrict__ Weff,
                           const float* __restrict__ beff, const float* __restrict__ embz,
                           short* __restrict__ PQ, short* __restrict__ PKf,
                           short* __restrict__ PVt, int CH) {
  __shared__ short As[64 * LDT];
  __shared__ short Bs[64 * LDT];
  int mt = blockIdx.x % 25, cg = blockIdx.x / 25;
  int mat = blockIdx.y >> 3, n0 = (blockIdx.y & 7) * 64;
  int b = cg / CH, ch = cg % CH;
  int tid = threadIdx.x, lane = tid & 63, w = tid >> 6, wr = w >> 1, wc = w & 1;
  int sr = tid >> 2, sc = (tid & 3) * 8;
  int mloc = mt * 64 + sr;
  int pb = mloc < Pp ? mloc : (Pp - 1);
  int t3 = pb / 196, rm = pb % 196, h2 = rm / 14, w2 = rm % 14;
  int l0 = 1 + t3 * 784 + h2 * 56 + w2 * 2;
  const short* xb = xbf + (size_t)b * Ll * 512;
  const short* Wf = Weff + ((size_t)(mat * CH + ch) * 512) * 2048;
  f32x4 acc[2][2] = {};
  for (int kq = 0; kq < 2048; kq += 32) {
    int tap = kq >> 9;
    int lrow = l0 + (tap >> 1) * 28 + (tap & 1);
    *(short8*)(As + sr * LDT + sc) =
        *(const short8*)(xb + (size_t)lrow * 512 + (kq & 511) + sc);
    *(short8*)(Bs + sr * LDT + sc) =
        *(const short8*)(Wf + (size_t)(n0 + sr) * 2048 + kq + sc);
    __syncthreads();
    mma_step(As, Bs, lane, wr, wc, acc[0][0], acc[0][1], acc[1][0], acc[1][1]);
    __syncthreads();
  }
  int m = lane & 15, quad = lane >> 4;
  const float* be = beff + (mat * CH + ch) * 512;
  #pragma unroll
  for (int ri = 0; ri < 2; ++ri)
    #pragma unroll
    for (int ci = 0; ci < 2; ++ci)
      #pragma unroll
      for (int e = 0; e < 4; ++e) {
        int mrow = mt * 64 + wr * 32 + ri * 16 + quad * 4 + e;
        int tok = mrow + 1; if (tok > LP - 1) tok = LP - 1;
        int n = n0 + wc * 32 + ci * 16 + m;
        float v = acc[ri][ci][e] + be[n];
        if (mat == 0)      PQ[((size_t)cg * LP + tok) * 512 + n] = f2bs(v);
        else if (mat == 1) PKf[((size_t)cg * LP + tok) * 512 + n] =
                               f2bs(v * QK_SCALE + embz[(size_t)tok * 512 + n]);
        else               PVt[((size_t)cg * 512 + n) * LP + tok] = f2bs(v);
      }
}

// PX pooled GEMM (no bias), cg = b
__global__ void px_pool(const short* __restrict__ xbf, const short* __restrict__ wpxT,
                        short* __restrict__ PX) {
  __shared__ short As[64 * LDT];
  __shared__ short Bs[64 * LDT];
  int mt = blockIdx.x % 25, b = blockIdx.x / 25;
  int n0 = blockIdx.y * 64;
  int tid = threadIdx.x, lane = tid & 63, w = tid >> 6, wr = w >> 1, wc = w & 1;
  int sr = tid >> 2, sc = (tid & 3) * 8;
  int mloc = mt * 64 + sr;
  int pb = mloc < Pp ? mloc : (Pp - 1);
  int t3 = pb / 196, rm = pb % 196, h2 = rm / 14, w2 = rm % 14;
  int l0 = 1 + t3 * 784 + h2 * 56 + w2 * 2;
  const short* xb = xbf + (size_t)b * Ll * 512;
  f32x4 acc[2][2] = {};
  for (int kq = 0; kq < 2048; kq += 32) {
    int tap = kq >> 9;
    int lrow = l0 + (tap >> 1) * 28 + (tap & 1);
    *(short8*)(As + sr * LDT + sc) =
        *(const short8*)(xb + (size_t)lrow * 512 + (kq & 511) + sc);
    *(short8*)(Bs + sr * LDT + sc) =
        *(const short8*)(wpxT + (size_t)(n0 + sr) * 2048 + kq + sc);
    __syncthreads();
    mma_step(As, Bs, lane, wr, wc, acc[0][0], acc[0][1], acc[1][0], acc[1][1]);
    __syncthreads();
  }
  int m = lane & 15, quad = lane >> 4;
  #pragma unroll
  for (int ri = 0; ri < 2; ++ri)
    #pragma unroll
    for (int ci = 0; ci < 2; ++ci)
      #pragma unroll
      for (int e = 0; e < 4; ++e) {
        int mrow = mt * 64 + wr * 32 + ri * 16 + quad * 4 + e;
        int tok = mrow + 1; if (tok > LP - 1) tok = LP - 1;
        int n = n0 + wc * 32 + ci * 16 + m;
        PX[((size_t)b * LP + tok) * 512 + n] = f2bs(acc[ri][ci][e]);
      }
}

// cls row (token 0): one wave per output dot product. grid(128, 3, 2CH)
__global__ void cls_fast(const short* __restrict__ xbf,
                         const float* __restrict__ Wq, const float* __restrict__ bq,
                         const float* __restrict__ Wk, const float* __restrict__ bk,
                         const float* __restrict__ Wv, const float* __restrict__ bv,
                         int h0, int CH,
                         short* __restrict__ PQ, short* __restrict__ PKf,
                         short* __restrict__ PVt) {
  int cg = blockIdx.z, mat = blockIdx.y;
  int wv = threadIdx.x >> 6, lane = threadIdx.x & 63;
  int n = blockIdx.x * 4 + wv;
  int b = cg / CH, h = h0 + cg % CH;
  const float* W = mat == 0 ? Wq : (mat == 1 ? Wk : Wv);
  const float* bias = mat == 0 ? bq : (mat == 1 ? bk : bv);
  const short* xr = xbf + (size_t)b * Ll * 512;
  const float* wr = W + ((size_t)(h * 512 + n)) * 512;
  float s = 0.f;
  #pragma unroll
  for (int j = 0; j < 8; ++j) {
    int k = lane * 8 + j;
    s += bs2f(xr[k]) * wr[k];
  }
  #pragma unroll
  for (int off = 32; off; off >>= 1) s += __shfl_down(s, off, 64);
  if (lane == 0) {
    s += bias[h * 512 + n];
    if (mat == 0)      PQ[((size_t)cg * LP) * 512 + n] = f2bs(s);
    else if (mat == 1) PKf[((size_t)cg * LP) * 512 + n] = f2bs(s * QK_SCALE);
    else               PVt[((size_t)cg * 512 + n) * LP] = f2bs(s);
  }
}

// PX cls row
__global__ void pxcls_kernel(const float* __restrict__ x, short* __restrict__ PX) {
  int b = blockIdx.x, n = threadIdx.x;
  PX[(size_t)b * LP * 512 + n] = f2bs(x[(size_t)b * Ll * 512 + n]);
}

// cfx[cg][kt] = dot(PQ[cg,0,:], embz[kt,:])
__global__ void cfix_kernel(const short* __restrict__ PQ, const float* __restrict__ embz,
                            int a0, float* __restrict__ cfx) {
  int cg = a0 + blockIdx.y;
  int wv = threadIdx.x >> 6, lane = threadIdx.x & 63;
  int kt = blockIdx.x * 4 + wv;
  if (kt >= LP) return;
  int ktc = kt < LL2 ? kt : (LL2 - 1);
  const short* q0 = PQ + (size_t)cg * LP * 512;
  const float* e = embz + (size_t)ktc * 512;
  float s = 0.f;
  #pragma unroll
  for (int j = 0; j < 8; ++j) {
    int d = lane * 8 + j;
    s += bs2f(q0[d]) * e[d];
  }
  #pragma unroll
  for (int off = 32; off; off >>= 1) s += __shfl_down(s, off, 64);
  if (lane == 0) cfx[(size_t)cg * LP + kt] = s;
}

// logits[z][q][kt] (f32) = PQ[a0+z] . PKf[a0+z]; row0 -= cfx
__global__ void logits_mfma(const short* __restrict__ PQ, const short* __restrict__ PKf,
                            const float* __restrict__ cfx, int a0, float* __restrict__ Lg) {
  __shared__ short As[64 * LDT];
  __shared__ short Bs[64 * LDT];
  int q0 = blockIdx.x * 64, k0 = blockIdx.y * 64, z = blockIdx.z;
  int cg = a0 + z;
  int tid = threadIdx.x, lane = tid & 63, w = tid >> 6, wr = w >> 1, wc = w & 1;
  int sr = tid >> 2, sc = (tid & 3) * 8;
  const short* Aq = PQ + (size_t)cg * LP * 512;
  const short* Bk = PKf + (size_t)cg * LP * 512;
  f32x4 acc[2][2] = {};
  for (int kd = 0; kd < 512; kd += 32) {
    *(short8*)(As + sr * LDT + sc) = *(const short8*)(Aq + (size_t)(q0 + sr) * 512 + kd + sc);
    *(short8*)(Bs + sr * LDT + sc) = *(const short8*)(Bk + (size_t)(k0 + sr) * 512 + kd + sc);
    __syncthreads();
    mma_step(As, Bs, lane, wr, wc, acc[0][0], acc[0][1], acc[1][0], acc[1][1]);
    __syncthreads();
  }
  int m = lane & 15, quad = lane >> 4;
  float* lg = Lg + (size_t)z * LP * LP;
  const float* cf = cfx + (size_t)cg * LP;
  #pragma unroll
  for (int ri = 0; ri < 2; ++ri)
    #pragma unroll
    for (int ci = 0; ci < 2; ++ci)
      #pragma unroll
      for (int e = 0; e < 4; ++e) {
        int q = q0 + wr * 32 + ri * 16 + quad * 4 + e;
        int kt = k0 + wc * 32 + ci * 16 + m;
        float v = acc[ri][ci][e];
        if (q == 0) v -= cf[kt];
        lg[(size_t)q * LP + kt] = v;
      }
}

// softmax row (f32) -> bf16 attn in place
__global__ void softmax_kernel(float* __restrict__ Lg) {
  int q = blockIdx.x, z = blockIdx.y;
  float* p = Lg + ((size_t)z * LP + q) * LP;
  __shared__ float buf[LP];
  __shared__ float red[256];
  int tid = threadIdx.x;
  float mx = -1e30f;
  for (int j = tid; j < LL2; j += 256) { float v = p[j]; buf[j] = v; mx = fmaxf(mx, v); }
  red[tid] = mx; __syncthreads();
  for (int s = 128; s; s >>= 1) { if (tid < s) red[tid] = fmaxf(red[tid], red[tid + s]); __syncthreads(); }
  mx = red[0]; __syncthreads();
  float sum = 0.f;
  for (int j = tid; j < LL2; j += 256) { float e = __expf(buf[j] - mx); buf[j] = e; sum += e; }
  red[tid] = sum; __syncthreads();
  for (int s = 128; s; s >>= 1) { if (tid < s) red[tid] += red[tid + s]; __syncthreads(); }
  float inv = 1.f / red[0];
  short* o = (short*)p;
  for (int j = tid; j < LL2; j += 256) o[j] = f2bs(buf[j] * inv);
  for (int j = LL2 + tid; j < LP; j += 256) o[j] = 0;
}

// Outb[gg][q][n] = attn @ PVt + (q==0?1:2)*PQ
__global__ void av_mfma(const float* __restrict__ Lg, const short* __restrict__ PVt,
                        const short* __restrict__ PQ, short* __restrict__ Outb,
                        int h0, int CH, int a0) {
  __shared__ short As[64 * LDT];
  __shared__ short Bs[64 * LDT];
  int q0 = blockIdx.x * 64, n0 = blockIdx.y * 64, z = blockIdx.z;
  int cg = a0 + z;
  int b = cg / CH, gg = b * 8 + h0 + cg % CH;
  int tid = threadIdx.x, lane = tid & 63, w = tid >> 6, wr = w >> 1, wc = w & 1;
  int sr = tid >> 2, sc = (tid & 3) * 8;
  const short* Aat = (const short*)(Lg + (size_t)z * LP * LP);  // bf16 rows, stride 2*LP
  const short* Bv = PVt + (size_t)cg * 512 * LP;
  f32x4 acc[2][2] = {};
  for (int kt = 0; kt < LP; kt += 32) {
    *(short8*)(As + sr * LDT + sc) = *(const short8*)(Aat + (size_t)(q0 + sr) * (2 * LP) + kt + sc);
    *(short8*)(Bs + sr * LDT + sc) = *(const short8*)(Bv + (size_t)(n0 + sr) * LP + kt + sc);
    __syncthreads();
    mma_step(As, Bs, lane, wr, wc, acc[0][0], acc[0][1], acc[1][0], acc[1][1]);
    __syncthreads();
  }
  int m = lane & 15, quad = lane >> 4;
  #pragma unroll
  for (int ri = 0; ri < 2; ++ri)
    #pragma unroll
    for (int ci = 0; ci < 2; ++ci)
      #pragma unroll
      for (int e = 0; e < 4; ++e) {
        int q = q0 + wr * 32 + ri * 16 + quad * 4 + e;
        if (q >= LL2) continue;
        int n = n0 + wc * 32 + ci * 16 + m;
        float res = bs2f(PQ[((size_t)cg * LP + q) * 512 + n]);
        float v = acc[ri][ci][e] + (q == 0 ? 1.f : 2.f) * res;
        Outb[((size_t)gg * LP + q) * 512 + n] = f2bs(v);
      }
}

// Y = stacked @ Wd^T + bd + PX   (WdB pre-converted bf16, B-layout already)
__global__ void final_mfma(const short* __restrict__ Outb, const short* __restrict__ WdB,
                           const float* __restrict__ bd, const short* __restrict__ PX,
                           float* __restrict__ Y) {
  __shared__ short As[64 * LDT];
  __shared__ short Bs[64 * LDT];
  int mt = blockIdx.x % 25, b = blockIdx.x / 25;
  int n0 = blockIdx.y * 64;
  int tid = threadIdx.x, lane = tid & 63, w = tid >> 6, wr = w >> 1, wc = w & 1;
  int sr = tid >> 2, sc = (tid & 3) * 8;
  int qrow = mt * 64 + sr; if (qrow > LL2 - 1) qrow = LL2 - 1;
  f32x4 acc[2][2] = {};
  for (int kq = 0; kq < 4096; kq += 32) {
    int hh = kq >> 9;
    *(short8*)(As + sr * LDT + sc) =
        *(const short8*)(Outb + ((size_t)(b * 8 + hh) * LP + qrow) * 512 + (kq & 511) + sc);
    *(short8*)(Bs + sr * LDT + sc) =
        *(const short8*)(WdB + (size_t)(n0 + sr) * 4096 + kq + sc);
    __syncthreads();
    mma_step(As, Bs, lane, wr, wc, acc[0][0], acc[0][1], acc[1][0], acc[1][1]);
    __syncthreads();
  }
  int m = lane & 15, quad = lane >> 4;
  #pragma unroll
  for (int ri = 0; ri < 2; ++ri)
    #pragma unroll
    for (int ci = 0; ci < 2; ++ci)
      #pragma unroll
      for (int e = 0; e < 4; ++e) {
        int q = mt * 64 + wr * 32 + ri * 16 + quad * 4 + e;
        if (q >= LL2) continue;
        int dm = n0 + wc * 32 + ci * 16 + m;
        float v = acc[ri][ci][e] + bd[dm] + bs2f(PX[((size_t)b * LP + q) * 512 + dm]);
        Y[((size_t)(b * LL2 + q)) * 512 + dm] = v;
      }
}

// LayerNorm over 512
__global__ void ln_kernel(const float* __restrict__ Y, const float* __restrict__ gamma,
                          const float* __restrict__ beta, float* __restrict__ Outp) {
  int row = blockIdx.x;
  const float* y = Y + (size_t)row * 512;
  __shared__ float red[256];
  int tid = threadIdx.x;
  float v0 = y[tid], v1 = y[tid + 256];
  red[tid] = v0 + v1; __syncthreads();
  for (int s = 128; s; s >>= 1) { if (tid < s) red[tid] += red[tid + s]; __syncthreads(); }
  float mu = red[0] * (1.f / 512.f);
  __syncthreads();
  float d0 = v0 - mu, d1 = v1 - mu;
  red[tid] = d0 * d0 + d1 * d1; __syncthreads();
  for (int s = 128; s; s >>= 1) { if (tid < s) red[tid] += red[tid + s]; __syncthreads(); }
  float rstd = rsqrtf(red[0] * (1.f / 512.f) + 1e-5f);
  float* o = Outp + (size_t)row * 512;
  o[tid]       = d0 * rstd * gamma[tid]       + beta[tid];
  o[tid + 256] = d1 * rstd * gamma[tid + 256] + beta[tid + 256];
}

// ---------------------------------------------------------------------------
extern "C" void kernel_launch(void* const* d_in, const int* in_sizes, int n_in,
                              void* d_out, int out_size, void* d_ws, size_t ws_size,
                              hipStream_t stream) {
  const float* x     = (const float*)d_in[0];
  const float* Wq    = (const float*)d_in[1];
  const float* bq    = (const float*)d_in[2];
  const float* Wk    = (const float*)d_in[3];
  const float* bk    = (const float*)d_in[4];
  const float* Wv    = (const float*)d_in[5];
  const float* bv    = (const float*)d_in[6];
  const float* wpq   = (const float*)d_in[7];
  const float* wpk   = (const float*)d_in[8];
  const float* wpv   = (const float*)d_in[9];
  const float* wpx   = (const float*)d_in[10];
  const float* Wd    = (const float*)d_in[11];
  const float* bd    = (const float*)d_in[12];
  const float* gamma = (const float*)d_in[13];
  const float* beta  = (const float*)d_in[14];
  float* outp = (float*)d_out;

  auto rnd = [](size_t b) { return (b + 255) / 256 * 256; };
  const size_t persist =
      rnd((size_t)LP * 512 * 4) +            // embz
      rnd((size_t)Bb * Ll * 512 * 2) +       // xbf
      rnd((size_t)512 * 2048 * 2) +          // wpxT
      3 * rnd((size_t)8 * 512 * 512 * 2) +   // WqT/WkT/WvT
      rnd((size_t)512 * 4096 * 2) +          // WdB
      rnd((size_t)16 * LP * 512 * 2) +       // Outb
      rnd((size_t)2 * LP * 512 * 2) +        // PX
      rnd((size_t)2 * LL2 * 512 * 4) +       // Y
      rnd((size_t)16 * LP * 4);              // cfx
  auto chpart = [&](int CH) {
    return rnd((size_t)3 * CH * 512 * 2048 * 2) + rnd((size_t)3 * CH * 512 * 4) +
           3 * rnd((size_t)2 * CH * LP * 512 * 2);
  };
  const size_t lgbytes = rnd((size_t)LP * LP * 4);
  int CH = 8;
  while (CH > 1 && persist + chpart(CH) + lgbytes > ws_size) CH >>= 1;
  if (persist + chpart(CH) + lgbytes > ws_size) return;  // needs ~97 MB min
  int NA = (int)((ws_size - persist - chpart(CH)) / lgbytes);
  if (NA > 2 * CH) NA = 2 * CH;
  int nc = 8 / CH;

  char* w = (char*)d_ws;
  auto alloc = [&](size_t bytes) { char* p = w; w += (bytes + 255) / 256 * 256; return p; };
  float* embz = (float*)alloc((size_t)LP * 512 * 4);
  short* xbf  = (short*)alloc((size_t)Bb * Ll * 512 * 2);
  short* wpxT = (short*)alloc((size_t)512 * 2048 * 2);
  short* WqT  = (short*)alloc((size_t)8 * 512 * 512 * 2);
  short* WkT  = (short*)alloc((size_t)8 * 512 * 512 * 2);
  short* WvT  = (short*)alloc((size_t)8 * 512 * 512 * 2);
  short* WdB  = (short*)alloc((size_t)512 * 4096 * 2);
  short* Outb = (short*)alloc((size_t)16 * LP * 512 * 2);
  short* PX   = (short*)alloc((size_t)2 * LP * 512 * 2);
  float* Y    = (float*)alloc((size_t)2 * LL2 * 512 * 4);
  float* cfx  = (float*)alloc((size_t)16 * LP * 4);
  short* Weff = (short*)alloc((size_t)3 * CH * 512 * 2048 * 2);
  float* beff = (float*)alloc((size_t)3 * CH * 512 * 4);
  short* PQ   = (short*)alloc((size_t)2 * CH * LP * 512 * 2);
  short* PKf  = (short*)alloc((size_t)2 * CH * LP * 512 * 2);
  short* PVt  = (short*)alloc((size_t)2 * CH * LP * 512 * 2);
  float* Lg   = (float*)alloc((size_t)NA * LP * LP * 4);

  dim3 blk(256);
  emb_kernel<<<dim3((LP * 512 + 255) / 256), blk, 0, stream>>>(embz);
  cvt_kernel<<<dim3((Bb * Ll * 512 / 4 + 255) / 256), blk, 0, stream>>>(x, xbf, Bb * Ll * 512 / 4);
  wpxt_kernel<<<dim3((512 * 2048 + 255) / 256), blk, 0, stream>>>(wpx, wpxT);
  tr_w_kernel<<<dim3(8, 8, 8), blk, 0, stream>>>(Wq, WqT);
  tr_w_kernel<<<dim3(8, 8, 8), blk, 0, stream>>>(Wk, WkT);
  tr_w_kernel<<<dim3(8, 8, 8), blk, 0, stream>>>(Wv, WvT);
  cvt_kernel<<<dim3((512 * 4096 / 4 + 255) / 256), blk, 0, stream>>>(Wd, WdB, 512 * 4096 / 4);
  px_pool<<<dim3(50, 8), blk, 0, stream>>>(xbf, wpxT, PX);
  pxcls_kernel<<<dim3(2), dim3(512), 0, stream>>>(x, PX);

  for (int c = 0; c < nc; ++c) {
    int h0 = c * CH;
    weff_fused<<<dim3(8, 8, 12 * CH), blk, 0, stream>>>(wpq, wpk, wpv, WqT, WkT, WvT,
                                                        h0, CH, Weff);
    beff_fused<<<dim3(3, CH), blk, 0, stream>>>(bq, bk, bv, wpq, wpk, wpv, h0, CH, beff);
    pool_fused<<<dim3(25 * 2 * CH, 24), blk, 0, stream>>>(xbf, Weff, beff, embz,
                                                          PQ, PKf, PVt, CH);
    cls_fast<<<dim3(128, 3, 2 * CH), blk, 0, stream>>>(xbf, Wq, bq, Wk, bk, Wv, bv,
                                                       h0, CH, PQ, PKf, PVt);
    for (int a0 = 0; a0 < 2 * CH; a0 += NA) {
      int na = (2 * CH - a0) < NA ? (2 * CH - a0) : NA;
      cfix_kernel<<<dim3(400, na), blk, 0, stream>>>(PQ, embz, a0, cfx);
      logits_mfma<<<dim3(25, 25, na), blk, 0, stream>>>(PQ, PKf, cfx, a0, Lg);
      softmax_kernel<<<dim3(LL2, na), blk, 0, stream>>>(Lg);
      av_mfma<<<dim3(25, 8, na), blk, 0, stream>>>(Lg, PVt, PQ, Outb, h0, CH, a0);
    }
  }

  final_mfma<<<dim3(50, 8), blk, 0, stream>>>(Outb, WdB, bd, PX, Y);
  ln_kernel<<<dim3(Bb * LL2), blk, 0, stream>>>(Y, gamma, beta, outp);
}

// Round 7
// 1085.255 us; speedup vs baseline: 21.8805x; 1.5321x over previous
//
#include <hip/hip_runtime.h>
#include <hip/hip_bf16.h>
#include <cstdint>
#include <cstddef>

typedef __hip_bfloat16 bf16;
typedef __attribute__((ext_vector_type(8))) short short8;   // 8 bf16 in 4 VGPRs
typedef __attribute__((ext_vector_type(4))) short short4v;
typedef __attribute__((ext_vector_type(4))) float f32x4;
#define DEVI __device__ __forceinline__

constexpr int Bb = 2, Ll = 6273, Pp = 1568, LL2 = 1569, LP = 1600;
constexpr float QK_SCALE = 0.04419417382415922f;  // 512^-0.5

DEVI short f2bs(float f) {
  __hip_bfloat16 h = __float2bfloat16(f);
  return __builtin_bit_cast(short, h);
}
DEVI float bs2f(short s) {
  __hip_bfloat16 h = __builtin_bit_cast(__hip_bfloat16, s);
  return __bfloat162float(h);
}

// ===========================================================================
// 128x128 MFMA tile core, BK=64, 256 threads = 4 waves in 2x2 (each 64x64 via
// 4x4 frags of mfma_f32_16x16x32_bf16). LDS 128x64 shorts per tile, 16B-slot
// XOR swizzle (slot ^= row&7) -> conflict-minimal b128 reads.
// C/D layout per m89: col=lane&15, row=quad*4+e.
// ===========================================================================
constexpr int BK = 64;

DEVI int sw_idx(int row, int slot) {            // slot = 16B unit (8 shorts)
  return row * BK + (((slot) ^ (row & 7)) << 3);
}

DEVI void mma128(const short* As, const short* Bs, int lane, int wr, int wc,
                 f32x4 (&acc)[4][4]) {
  int m = lane & 15, quad = lane >> 4;
  #pragma unroll
  for (int kh = 0; kh < 2; ++kh) {
    int slot = kh * 4 + quad;
    short8 a[4], b[4];
    #pragma unroll
    for (int i = 0; i < 4; ++i) {
      int row = wr * 64 + i * 16 + m;
      a[i] = *(const short8*)(As + sw_idx(row, slot));
    }
    #pragma unroll
    for (int j = 0; j < 4; ++j) {
      int row = wc * 64 + j * 16 + m;
      b[j] = *(const short8*)(Bs + sw_idx(row, slot));
    }
    #pragma unroll
    for (int i = 0; i < 4; ++i)
      #pragma unroll
      for (int j = 0; j < 4; ++j)
        acc[i][j] = __builtin_amdgcn_mfma_f32_16x16x32_bf16(a[i], b[j], acc[i][j], 0, 0, 0);
  }
}

// Old 64x64 core (kept for the small px_pool only)
constexpr int LDT = 40;
DEVI void mma_step(const short* As, const short* Bs, int lane, int wr, int wc,
                   f32x4& c00, f32x4& c01, f32x4& c10, f32x4& c11) {
  int m = lane & 15, quad = lane >> 4;
  const short* a = As + (wr * 32 + m) * LDT + quad * 8;
  const short* b = Bs + (wc * 32 + m) * LDT + quad * 8;
  short8 a0 = *(const short8*)a;
  short8 a1 = *(const short8*)(a + 16 * LDT);
  short8 b0 = *(const short8*)b;
  short8 b1 = *(const short8*)(b + 16 * LDT);
  c00 = __builtin_amdgcn_mfma_f32_16x16x32_bf16(a0, b0, c00, 0, 0, 0);
  c01 = __builtin_amdgcn_mfma_f32_16x16x32_bf16(a0, b1, c01, 0, 0, 0);
  c10 = __builtin_amdgcn_mfma_f32_16x16x32_bf16(a1, b0, c10, 0, 0, 0);
  c11 = __builtin_amdgcn_mfma_f32_16x16x32_bf16(a1, b1, c11, 0, 0, 0);
}

// ---------------------------------------------------------------------------
__global__ void emb_kernel(float* __restrict__ embz) {
  int idx = blockIdx.x * 256 + threadIdx.x;
  if (idx >= LP * 512) return;
  int p = idx >> 9, d = idx & 511;
  float v = 0.f;
  if (p > 0 && p < LL2) {
    int pb = p - 1;
    int t = pb / 196, r = pb % 196;
    int h = r / 14, ww = r % 14;
    int pos, j, half;
    if (d < 170)      { pos = t;  j = d;       half = 85; }
    else if (d < 340) { pos = h;  j = d - 170; half = 85; }
    else              { pos = ww; j = d - 340; half = 86; }
    int jj = (j < half) ? j : (j - half);
    float omega = powf(10000.f, -(float)jj / (float)half);
    float ang = (float)pos * omega;
    v = (j < half) ? sinf(ang) : cosf(ang);
  }
  embz[idx] = v;
}

// f32 -> bf16 bulk convert, 4 elements/thread
__global__ void cvt_kernel(const float* __restrict__ src, short* __restrict__ dst, int n4) {
  int idx = blockIdx.x * 256 + threadIdx.x;
  if (idx >= n4) return;
  float4 v = *(const float4*)(src + (size_t)idx * 4);
  short4v o = { f2bs(v.x), f2bs(v.y), f2bs(v.z), f2bs(v.w) };
  *(short4v*)(dst + (size_t)idx * 4) = o;
}

// wpT[n][tap*512+k] = bf16(wp[n*2048 + k*4 + tap])  (works for wpx/wpq/wpk/wpv)
__global__ void wpxt_kernel(const float* __restrict__ wp, short* __restrict__ wpT) {
  int idx = blockIdx.x * 256 + threadIdx.x;
  if (idx >= 512 * 2048) return;
  int n = idx >> 11, rem = idx & 2047, tap = rem >> 9, k = rem & 511;
  wpT[idx] = f2bs(wp[n * 2048 + k * 4 + tap]);
}

// WT[h][k][i] = bf16(W[(h*512+i)*512 + k])
__global__ void tr_w_kernel(const float* __restrict__ W, short* __restrict__ WT) {
  __shared__ float Ws[64][65];
  int i0 = blockIdx.x * 64, k0 = blockIdx.y * 64, h = blockIdx.z;
  int tid = threadIdx.x;
  int r = tid >> 2, c0 = (tid & 3) * 16;
  const float* src = W + ((size_t)(h * 512 + i0 + r)) * 512 + k0 + c0;
  #pragma unroll
  for (int j = 0; j < 16; ++j) Ws[r][c0 + j] = src[j];
  __syncthreads();
  short* dst = WT + ((size_t)(h * 512 + k0 + r)) * 512 + i0 + c0;
  #pragma unroll
  for (int j = 0; j < 16; ++j) dst[j] = f2bs(Ws[c0 + j][r]);
}

// ===========================================================================
// weff128: Weff[(mat*CH+ch)*512+n][tap*512+k] = sum_i wpT[n][tap*512+i]*WT[h][k][i]
// grid (4, 4, 12*CH)
// ===========================================================================
__global__ void weff128(const short* __restrict__ wpqT, const short* __restrict__ wpkT,
                        const short* __restrict__ wpvT,
                        const short* __restrict__ WqT, const short* __restrict__ WkT,
                        const short* __restrict__ WvT,
                        int h0, int CH, short* __restrict__ Weff) {
  __shared__ short As[128 * BK];
  __shared__ short Bs[128 * BK];
  int n0 = blockIdx.x * 128, k0 = blockIdx.y * 128;
  int z = blockIdx.z;
  int mat = z / (4 * CH), rem = z % (4 * CH);
  int ch = rem >> 2, tap = rem & 3;
  const short* wpT = mat == 0 ? wpqT : (mat == 1 ? wpkT : wpvT);
  const short* WT  = mat == 0 ? WqT  : (mat == 1 ? WkT  : WvT);
  int h = h0 + ch;
  int tid = threadIdx.x, lane = tid & 63, w = tid >> 6, wr = w >> 1, wc = w & 1;
  int s8 = (tid & 7) * 8, rbase = tid >> 3;
  f32x4 acc[4][4] = {};
  for (int kq = 0; kq < 512; kq += BK) {
    #pragma unroll
    for (int p = 0; p < 4; ++p) {
      int row = rbase + 32 * p;
      *(short8*)(As + sw_idx(row, s8 >> 3)) =
          *(const short8*)(wpT + (size_t)(n0 + row) * 2048 + tap * 512 + kq + s8);
      *(short8*)(Bs + sw_idx(row, s8 >> 3)) =
          *(const short8*)(WT + ((size_t)(h * 512 + k0 + row)) * 512 + kq + s8);
    }
    __syncthreads();
    mma128(As, Bs, lane, wr, wc, acc);
    __syncthreads();
  }
  int m = lane & 15, quad = lane >> 4;
  size_t base = ((size_t)(mat * CH + ch) * 512) * 2048 + tap * 512;
  #pragma unroll
  for (int i = 0; i < 4; ++i)
    #pragma unroll
    for (int j = 0; j < 4; ++j)
      #pragma unroll
      for (int e = 0; e < 4; ++e) {
        int n = n0 + wr * 64 + i * 16 + quad * 4 + e;
        int k = k0 + wc * 64 + j * 16 + m;
        Weff[base + (size_t)n * 2048 + k] = f2bs(acc[i][j][e]);
      }
}

// beff_all[(mat*CH+ch)][n]
__global__ void beff_fused(const float* __restrict__ bq, const float* __restrict__ bk,
                           const float* __restrict__ bv,
                           const float* __restrict__ wpq, const float* __restrict__ wpk,
                           const float* __restrict__ wpv,
                           int h0, int CH, float* __restrict__ beff) {
  int mat = blockIdx.x, ch = blockIdx.y, tid = threadIdx.x;
  const float* bias = mat == 0 ? bq : (mat == 1 ? bk : bv);
  const float* wp = mat == 0 ? wpq : (mat == 1 ? wpk : wpv);
  for (int n = tid; n < 512; n += 256) {
    float s = 0.f;
    for (int i = 0; i < 512; ++i) {
      float bi = bias[(h0 + ch) * 512 + i];
      const float* w4 = wp + (size_t)n * 2048 + i * 4;
      s += bi * (w4[0] + w4[1] + w4[2] + w4[3]);
    }
    beff[(mat * CH + ch) * 512 + n] = s;
  }
}

// ===========================================================================
// pool128: flattened GEMM  M=(13 m-tiles x 2 b), Nflat=3*CH*512, K=2048.
// XCD swizzle clusters same-A blocks: v=ell&7 owns mb in [4v,4v+4).
// grid 1D: 8*4*(12*CH) blocks.
// ===========================================================================
__global__ void pool128(const short* __restrict__ xbf, const short* __restrict__ Weff,
                        const float* __restrict__ beff, const float* __restrict__ embz,
                        short* __restrict__ PQ, short* __restrict__ PKf,
                        short* __restrict__ PVt, int CH) {
  int ell = blockIdx.x;
  int v = ell & 7, u = ell >> 3;
  int NT = 12 * CH;
  int nt = u % NT, mbl = u / NT;
  int mb = v * 4 + mbl;
  if (mb >= 26) return;
  int mt = mb % 13, b = mb / 13;
  int mat = nt / (4 * CH), ch = (nt >> 2) % CH;
  int n0t = (nt & 3) * 128;
  int cg = b * CH + ch;

  __shared__ short As[128 * BK];
  __shared__ short Bs[128 * BK];
  int tid = threadIdx.x, lane = tid & 63, w = tid >> 6, wr = w >> 1, wc = w & 1;
  int s8 = (tid & 7) * 8, rbase = tid >> 3;
  // prologue: pooled-position row bases for the 4 staged rows
  int l0r[4];
  #pragma unroll
  for (int p = 0; p < 4; ++p) {
    int row = rbase + 32 * p;
    int pb = mt * 128 + row; if (pb > Pp - 1) pb = Pp - 1;
    int t3 = pb / 196, rm = pb % 196, h2 = rm / 14, w2 = rm % 14;
    l0r[p] = 1 + t3 * 784 + h2 * 56 + w2 * 2;
  }
  const short* xb = xbf + (size_t)b * Ll * 512;
  const int taprow[4] = {0, 1, 28, 29};
  f32x4 acc[4][4] = {};
  for (int kq = 0; kq < 2048; kq += BK) {
    int tap = kq >> 9, koff = kq & 511;
    #pragma unroll
    for (int p = 0; p < 4; ++p) {
      int row = rbase + 32 * p;
      int lrow = l0r[p] + taprow[tap];
      *(short8*)(As + sw_idx(row, s8 >> 3)) =
          *(const short8*)(xb + (size_t)lrow * 512 + koff + s8);
      *(short8*)(Bs + sw_idx(row, s8 >> 3)) =
          *(const short8*)(Weff + ((size_t)nt * 128 + row) * 2048 + kq + s8);
    }
    __syncthreads();
    mma128(As, Bs, lane, wr, wc, acc);
    __syncthreads();
  }
  int m = lane & 15, quad = lane >> 4;
  #pragma unroll
  for (int i = 0; i < 4; ++i)
    #pragma unroll
    for (int j = 0; j < 4; ++j)
      #pragma unroll
      for (int e = 0; e < 4; ++e) {
        int row = wr * 64 + i * 16 + quad * 4 + e;
        int pb = mt * 128 + row;
        if (pb >= Pp) continue;
        int tok = pb + 1;
        int colLocal = wc * 64 + j * 16 + m;
        int n = n0t + colLocal;
        float val = acc[i][j][e] + beff[nt * 128 + colLocal];
        if (mat == 0)      PQ[((size_t)cg * LP + tok) * 512 + n] = f2bs(val);
        else if (mat == 1) PKf[((size_t)cg * LP + tok) * 512 + n] =
                               f2bs(val * QK_SCALE + embz[(size_t)tok * 512 + n]);
        else               PVt[((size_t)cg * 512 + n) * LP + tok] = f2bs(val);
      }
}

// PX pooled GEMM (64-tile; small)
__global__ void px_pool(const short* __restrict__ xbf, const short* __restrict__ wpxT,
                        short* __restrict__ PX) {
  __shared__ short As[64 * LDT];
  __shared__ short Bs[64 * LDT];
  int mt = blockIdx.x % 25, b = blockIdx.x / 25;
  int n0 = blockIdx.y * 64;
  int tid = threadIdx.x, lane = tid & 63, w = tid >> 6, wr = w >> 1, wc = w & 1;
  int sr = tid >> 2, sc = (tid & 3) * 8;
  int mloc = mt * 64 + sr;
  int pb = mloc < Pp ? mloc : (Pp - 1);
  int t3 = pb / 196, rm = pb % 196, h2 = rm / 14, w2 = rm % 14;
  int l0 = 1 + t3 * 784 + h2 * 56 + w2 * 2;
  const short* xb = xbf + (size_t)b * Ll * 512;
  f32x4 acc[2][2] = {};
  for (int kq = 0; kq < 2048; kq += 32) {
    int tap = kq >> 9;
    int lrow = l0 + (tap >> 1) * 28 + (tap & 1);
    *(short8*)(As + sr * LDT + sc) =
        *(const short8*)(xb + (size_t)lrow * 512 + (kq & 511) + sc);
    *(short8*)(Bs + sr * LDT + sc) =
        *(const short8*)(wpxT + (size_t)(n0 + sr) * 2048 + kq + sc);
    __syncthreads();
    mma_step(As, Bs, lane, wr, wc, acc[0][0], acc[0][1], acc[1][0], acc[1][1]);
    __syncthreads();
  }
  int m = lane & 15, quad = lane >> 4;
  #pragma unroll
  for (int ri = 0; ri < 2; ++ri)
    #pragma unroll
    for (int ci = 0; ci < 2; ++ci)
      #pragma unroll
      for (int e = 0; e < 4; ++e) {
        int mrow = mt * 64 + wr * 32 + ri * 16 + quad * 4 + e;
        int tok = mrow + 1; if (tok > LP - 1) tok = LP - 1;
        int n = n0 + wc * 32 + ci * 16 + m;
        PX[((size_t)b * LP + tok) * 512 + n] = f2bs(acc[ri][ci][e]);
      }
}

// cls row (token 0): one wave per output dot product. grid(128, 3, 2CH)
__global__ void cls_fast(const short* __restrict__ xbf,
                         const float* __restrict__ Wq, const float* __restrict__ bq,
                         const float* __restrict__ Wk, const float* __restrict__ bk,
                         const float* __restrict__ Wv, const float* __restrict__ bv,
                         int h0, int CH,
                         short* __restrict__ PQ, short* __restrict__ PKf,
                         short* __restrict__ PVt) {
  int cg = blockIdx.z, mat = blockIdx.y;
  int wv = threadIdx.x >> 6, lane = threadIdx.x & 63;
  int n = blockIdx.x * 4 + wv;
  int b = cg / CH, h = h0 + cg % CH;
  const float* W = mat == 0 ? Wq : (mat == 1 ? Wk : Wv);
  const float* bias = mat == 0 ? bq : (mat == 1 ? bk : bv);
  const short* xr = xbf + (size_t)b * Ll * 512;
  const float* wr = W + ((size_t)(h * 512 + n)) * 512;
  float s = 0.f;
  #pragma unroll
  for (int j = 0; j < 8; ++j) {
    int k = lane * 8 + j;
    s += bs2f(xr[k]) * wr[k];
  }
  #pragma unroll
  for (int off = 32; off; off >>= 1) s += __shfl_down(s, off, 64);
  if (lane == 0) {
    s += bias[h * 512 + n];
    if (mat == 0)      PQ[((size_t)cg * LP) * 512 + n] = f2bs(s);
    else if (mat == 1) PKf[((size_t)cg * LP) * 512 + n] = f2bs(s * QK_SCALE);
    else               PVt[((size_t)cg * 512 + n) * LP] = f2bs(s);
  }
}

// PX cls row
__global__ void pxcls_kernel(const float* __restrict__ x, short* __restrict__ PX) {
  int b = blockIdx.x, n = threadIdx.x;
  PX[(size_t)b * LP * 512 + n] = f2bs(x[(size_t)b * Ll * 512 + n]);
}

// cfx[cg][kt] = dot(PQ[cg,0,:], embz[kt,:])
__global__ void cfix_kernel(const short* __restrict__ PQ, const float* __restrict__ embz,
                            int a0, float* __restrict__ cfx) {
  int cg = a0 + blockIdx.y;
  int wv = threadIdx.x >> 6, lane = threadIdx.x & 63;
  int kt = blockIdx.x * 4 + wv;
  if (kt >= LP) return;
  int ktc = kt < LL2 ? kt : (LL2 - 1);
  const short* q0 = PQ + (size_t)cg * LP * 512;
  const float* e = embz + (size_t)ktc * 512;
  float s = 0.f;
  #pragma unroll
  for (int j = 0; j < 8; ++j) {
    int d = lane * 8 + j;
    s += bs2f(q0[d]) * e[d];
  }
  #pragma unroll
  for (int off = 32; off; off >>= 1) s += __shfl_down(s, off, 64);
  if (lane == 0) cfx[(size_t)cg * LP + kt] = s;
}

// ===========================================================================
// logits128: Lg[z][q][kt] = PQ[cg] . PKf[cg]; row0 -= cfx. grid (13,13,na)
// ===========================================================================
__global__ void logits128(const short* __restrict__ PQ, const short* __restrict__ PKf,
                          const float* __restrict__ cfx, int a0, float* __restrict__ Lg) {
  __shared__ short As[128 * BK];
  __shared__ short Bs[128 * BK];
  int q0 = blockIdx.x * 128, k0 = blockIdx.y * 128, z = blockIdx.z;
  int cg = a0 + z;
  int tid = threadIdx.x, lane = tid & 63, w = tid >> 6, wr = w >> 1, wc = w & 1;
  int s8 = (tid & 7) * 8, rbase = tid >> 3;
  const short* Aq = PQ + (size_t)cg * LP * 512;
  const short* Bk = PKf + (size_t)cg * LP * 512;
  f32x4 acc[4][4] = {};
  for (int kq = 0; kq < 512; kq += BK) {
    #pragma unroll
    for (int p = 0; p < 4; ++p) {
      int row = rbase + 32 * p;
      int ar = q0 + row; if (ar > LL2 - 1) ar = LL2 - 1;
      int br = k0 + row; if (br > LL2 - 1) br = LL2 - 1;
      *(short8*)(As + sw_idx(row, s8 >> 3)) = *(const short8*)(Aq + (size_t)ar * 512 + kq + s8);
      *(short8*)(Bs + sw_idx(row, s8 >> 3)) = *(const short8*)(Bk + (size_t)br * 512 + kq + s8);
    }
    __syncthreads();
    mma128(As, Bs, lane, wr, wc, acc);
    __syncthreads();
  }
  int m = lane & 15, quad = lane >> 4;
  float* lg = Lg + (size_t)z * LP * LP;
  const float* cf = cfx + (size_t)cg * LP;
  #pragma unroll
  for (int i = 0; i < 4; ++i)
    #pragma unroll
    for (int j = 0; j < 4; ++j)
      #pragma unroll
      for (int e = 0; e < 4; ++e) {
        int q = q0 + wr * 64 + i * 16 + quad * 4 + e;
        int kt = k0 + wc * 64 + j * 16 + m;
        if (q >= LP || kt >= LP) continue;
        float val = acc[i][j][e];
        if (q == 0) val -= cf[kt];
        lg[(size_t)q * LP + kt] = val;
      }
}

// softmax row (f32) -> bf16 attn in place
__global__ void softmax_kernel(float* __restrict__ Lg) {
  int q = blockIdx.x, z = blockIdx.y;
  float* p = Lg + ((size_t)z * LP + q) * LP;
  __shared__ float buf[LP];
  __shared__ float red[256];
  int tid = threadIdx.x;
  float mx = -1e30f;
  for (int j = tid; j < LL2; j += 256) { float v = p[j]; buf[j] = v; mx = fmaxf(mx, v); }
  red[tid] = mx; __syncthreads();
  for (int s = 128; s; s >>= 1) { if (tid < s) red[tid] = fmaxf(red[tid], red[tid + s]); __syncthreads(); }
  mx = red[0]; __syncthreads();
  float sum = 0.f;
  for (int j = tid; j < LL2; j += 256) { float e = __expf(buf[j] - mx); buf[j] = e; sum += e; }
  red[tid] = sum; __syncthreads();
  for (int s = 128; s; s >>= 1) { if (tid < s) red[tid] += red[tid + s]; __syncthreads(); }
  float inv = 1.f / red[0];
  short* o = (short*)p;
  for (int j = tid; j < LL2; j += 256) o[j] = f2bs(buf[j] * inv);
  for (int j = LL2 + tid; j < LP; j += 256) o[j] = 0;
}

// ===========================================================================
// av128: Outb[gg][q][n] = attn @ PVt + (q==0?1:2)*PQ. grid (13,4,na)
// ===========================================================================
__global__ void av128(const float* __restrict__ Lg, const short* __restrict__ PVt,
                      const short* __restrict__ PQ, short* __restrict__ Outb,
                      int h0, int CH, int a0) {
  __shared__ short As[128 * BK];
  __shared__ short Bs[128 * BK];
  int q0 = blockIdx.x * 128, n0 = blockIdx.y * 128, z = blockIdx.z;
  int cg = a0 + z;
  int b = cg / CH, gg = b * 8 + h0 + cg % CH;
  int tid = threadIdx.x, lane = tid & 63, w = tid >> 6, wr = w >> 1, wc = w & 1;
  int s8 = (tid & 7) * 8, rbase = tid >> 3;
  const short* Aat = (const short*)(Lg + (size_t)z * LP * LP);  // bf16 rows, stride 2*LP
  const short* Bv = PVt + (size_t)cg * 512 * LP;
  f32x4 acc[4][4] = {};
  for (int kq = 0; kq < LP; kq += BK) {
    #pragma unroll
    for (int p = 0; p < 4; ++p) {
      int row = rbase + 32 * p;
      int ar = q0 + row; if (ar > LP - 1) ar = LP - 1;
      *(short8*)(As + sw_idx(row, s8 >> 3)) =
          *(const short8*)(Aat + (size_t)ar * (2 * LP) + kq + s8);
      *(short8*)(Bs + sw_idx(row, s8 >> 3)) =
          *(const short8*)(Bv + (size_t)(n0 + row) * LP + kq + s8);
    }
    __syncthreads();
    mma128(As, Bs, lane, wr, wc, acc);
    __syncthreads();
  }
  int m = lane & 15, quad = lane >> 4;
  #pragma unroll
  for (int i = 0; i < 4; ++i)
    #pragma unroll
    for (int j = 0; j < 4; ++j)
      #pragma unroll
      for (int e = 0; e < 4; ++e) {
        int q = q0 + wr * 64 + i * 16 + quad * 4 + e;
        if (q >= LL2) continue;
        int n = n0 + wc * 64 + j * 16 + m;
        float res = bs2f(PQ[((size_t)cg * LP + q) * 512 + n]);
        float val = acc[i][j][e] + (q == 0 ? 1.f : 2.f) * res;
        Outb[((size_t)gg * LP + q) * 512 + n] = f2bs(val);
      }
}

// ===========================================================================
// final128: Y = stacked @ Wd^T + bd + PX. grid (25, 4). M=3138 flat (b,q).
// ===========================================================================
__global__ void final128(const short* __restrict__ Outb, const short* __restrict__ WdB,
                         const float* __restrict__ bd, const short* __restrict__ PX,
                         float* __restrict__ Y) {
  __shared__ short As[128 * BK];
  __shared__ short Bs[128 * BK];
  int mf0 = blockIdx.x * 128, n0 = blockIdx.y * 128;
  int tid = threadIdx.x, lane = tid & 63, w = tid >> 6, wr = w >> 1, wc = w & 1;
  int s8 = (tid & 7) * 8, rbase = tid >> 3;
  const int M = Bb * LL2;  // 3138
  int brow[4], qrow[4];
  #pragma unroll
  for (int p = 0; p < 4; ++p) {
    int mf = mf0 + rbase + 32 * p; if (mf > M - 1) mf = M - 1;
    brow[p] = mf / LL2; qrow[p] = mf % LL2;
  }
  f32x4 acc[4][4] = {};
  for (int kq = 0; kq < 4096; kq += BK) {
    int hh = kq >> 9, koff = kq & 511;
    #pragma unroll
    for (int p = 0; p < 4; ++p) {
      int row = rbase + 32 * p;
      *(short8*)(As + sw_idx(row, s8 >> 3)) =
          *(const short8*)(Outb + ((size_t)(brow[p] * 8 + hh) * LP + qrow[p]) * 512 + koff + s8);
      *(short8*)(Bs + sw_idx(row, s8 >> 3)) =
          *(const short8*)(WdB + (size_t)(n0 + row) * 4096 + kq + s8);
    }
    __syncthreads();
    mma128(As, Bs, lane, wr, wc, acc);
    __syncthreads();
  }
  int m = lane & 15, quad = lane >> 4;
  #pragma unroll
  for (int i = 0; i < 4; ++i)
    #pragma unroll
    for (int j = 0; j < 4; ++j)
      #pragma unroll
      for (int e = 0; e < 4; ++e) {
        int mf = mf0 + wr * 64 + i * 16 + quad * 4 + e;
        if (mf >= M) continue;
        int b2 = mf / LL2, q2 = mf % LL2;
        int dm = n0 + wc * 64 + j * 16 + m;
        float val = acc[i][j][e] + bd[dm] + bs2f(PX[((size_t)b2 * LP + q2) * 512 + dm]);
        Y[(size_t)mf * 512 + dm] = val;
      }
}

// LayerNorm over 512
__global__ void ln_kernel(const float* __restrict__ Y, const float* __restrict__ gamma,
                          const float* __restrict__ beta, float* __restrict__ Outp) {
  int row = blockIdx.x;
  const float* y = Y + (size_t)row * 512;
  __shared__ float red[256];
  int tid = threadIdx.x;
  float v0 = y[tid], v1 = y[tid + 256];
  red[tid] = v0 + v1; __syncthreads();
  for (int s = 128; s; s >>= 1) { if (tid < s) red[tid] += red[tid + s]; __syncthreads(); }
  float mu = red[0] * (1.f / 512.f);
  __syncthreads();
  float d0 = v0 - mu, d1 = v1 - mu;
  red[tid] = d0 * d0 + d1 * d1; __syncthreads();
  for (int s = 128; s; s >>= 1) { if (tid < s) red[tid] += red[tid + s]; __syncthreads(); }
  float rstd = rsqrtf(red[0] * (1.f / 512.f) + 1e-5f);
  float* o = Outp + (size_t)row * 512;
  o[tid]       = d0 * rstd * gamma[tid]       + beta[tid];
  o[tid + 256] = d1 * rstd * gamma[tid + 256] + beta[tid + 256];
}

// ---------------------------------------------------------------------------
extern "C" void kernel_launch(void* const* d_in, const int* in_sizes, int n_in,
                              void* d_out, int out_size, void* d_ws, size_t ws_size,
                              hipStream_t stream) {
  const float* x     = (const float*)d_in[0];
  const float* Wq    = (const float*)d_in[1];
  const float* bq    = (const float*)d_in[2];
  const float* Wk    = (const float*)d_in[3];
  const float* bk    = (const float*)d_in[4];
  const float* Wv    = (const float*)d_in[5];
  const float* bv    = (const float*)d_in[6];
  const float* wpq   = (const float*)d_in[7];
  const float* wpk   = (const float*)d_in[8];
  const float* wpv   = (const float*)d_in[9];
  const float* wpx   = (const float*)d_in[10];
  const float* Wd    = (const float*)d_in[11];
  const float* bd    = (const float*)d_in[12];
  const float* gamma = (const float*)d_in[13];
  const float* beta  = (const float*)d_in[14];
  float* outp = (float*)d_out;

  auto rnd = [](size_t b) { return (b + 255) / 256 * 256; };
  const size_t persist =
      rnd((size_t)LP * 512 * 4) +            // embz
      rnd((size_t)Bb * Ll * 512 * 2) +       // xbf
      4 * rnd((size_t)512 * 2048 * 2) +      // wpxT + wpqT/wpkT/wpvT
      3 * rnd((size_t)8 * 512 * 512 * 2) +   // WqT/WkT/WvT
      rnd((size_t)512 * 4096 * 2) +          // WdB
      rnd((size_t)16 * LP * 512 * 2) +       // Outb
      rnd((size_t)2 * LP * 512 * 2) +        // PX
      rnd((size_t)2 * LL2 * 512 * 4) +       // Y
      rnd((size_t)16 * LP * 4);              // cfx
  auto chpart = [&](int CH) {
    return rnd((size_t)3 * CH * 512 * 2048 * 2) + rnd((size_t)3 * CH * 512 * 4) +
           3 * rnd((size_t)2 * CH * LP * 512 * 2);
  };
  const size_t lgbytes = rnd((size_t)LP * LP * 4);
  int CH = 8;
  while (CH > 1 && persist + chpart(CH) + lgbytes > ws_size) CH >>= 1;
  if (persist + chpart(CH) + lgbytes > ws_size) return;
  int NA = (int)((ws_size - persist - chpart(CH)) / lgbytes);
  if (NA > 2 * CH) NA = 2 * CH;
  int nc = 8 / CH;

  char* w = (char*)d_ws;
  auto alloc = [&](size_t bytes) { char* p = w; w += (bytes + 255) / 256 * 256; return p; };
  float* embz = (float*)alloc((size_t)LP * 512 * 4);
  short* xbf  = (short*)alloc((size_t)Bb * Ll * 512 * 2);
  short* wpxT = (short*)alloc((size_t)512 * 2048 * 2);
  short* wpqT = (short*)alloc((size_t)512 * 2048 * 2);
  short* wpkT = (short*)alloc((size_t)512 * 2048 * 2);
  short* wpvT = (short*)alloc((size_t)512 * 2048 * 2);
  short* WqT  = (short*)alloc((size_t)8 * 512 * 512 * 2);
  short* WkT  = (short*)alloc((size_t)8 * 512 * 512 * 2);
  short* WvT  = (short*)alloc((size_t)8 * 512 * 512 * 2);
  short* WdB  = (short*)alloc((size_t)512 * 4096 * 2);
  short* Outb = (short*)alloc((size_t)16 * LP * 512 * 2);
  short* PX   = (short*)alloc((size_t)2 * LP * 512 * 2);
  float* Y    = (float*)alloc((size_t)2 * LL2 * 512 * 4);
  float* cfx  = (float*)alloc((size_t)16 * LP * 4);
  short* Weff = (short*)alloc((size_t)3 * CH * 512 * 2048 * 2);
  float* beff = (float*)alloc((size_t)3 * CH * 512 * 4);
  short* PQ   = (short*)alloc((size_t)2 * CH * LP * 512 * 2);
  short* PKf  = (short*)alloc((size_t)2 * CH * LP * 512 * 2);
  short* PVt  = (short*)alloc((size_t)2 * CH * LP * 512 * 2);
  float* Lg   = (float*)alloc((size_t)NA * LP * LP * 4);

  dim3 blk(256);
  emb_kernel<<<dim3((LP * 512 + 255) / 256), blk, 0, stream>>>(embz);
  cvt_kernel<<<dim3((Bb * Ll * 512 / 4 + 255) / 256), blk, 0, stream>>>(x, xbf, Bb * Ll * 512 / 4);
  wpxt_kernel<<<dim3(4096), blk, 0, stream>>>(wpx, wpxT);
  wpxt_kernel<<<dim3(4096), blk, 0, stream>>>(wpq, wpqT);
  wpxt_kernel<<<dim3(4096), blk, 0, stream>>>(wpk, wpkT);
  wpxt_kernel<<<dim3(4096), blk, 0, stream>>>(wpv, wpvT);
  tr_w_kernel<<<dim3(8, 8, 8), blk, 0, stream>>>(Wq, WqT);
  tr_w_kernel<<<dim3(8, 8, 8), blk, 0, stream>>>(Wk, WkT);
  tr_w_kernel<<<dim3(8, 8, 8), blk, 0, stream>>>(Wv, WvT);
  cvt_kernel<<<dim3((512 * 4096 / 4 + 255) / 256), blk, 0, stream>>>(Wd, WdB, 512 * 4096 / 4);
  px_pool<<<dim3(50, 8), blk, 0, stream>>>(xbf, wpxT, PX);
  pxcls_kernel<<<dim3(2), dim3(512), 0, stream>>>(x, PX);

  for (int c = 0; c < nc; ++c) {
    int h0 = c * CH;
    weff128<<<dim3(4, 4, 12 * CH), blk, 0, stream>>>(wpqT, wpkT, wpvT, WqT, WkT, WvT,
                                                     h0, CH, Weff);
    beff_fused<<<dim3(3, CH), blk, 0, stream>>>(bq, bk, bv, wpq, wpk, wpv, h0, CH, beff);
    pool128<<<dim3(8 * 4 * 12 * CH), blk, 0, stream>>>(xbf, Weff, beff, embz,
                                                       PQ, PKf, PVt, CH);
    cls_fast<<<dim3(128, 3, 2 * CH), blk, 0, stream>>>(xbf, Wq, bq, Wk, bk, Wv, bv,
                                                       h0, CH, PQ, PKf, PVt);
    for (int a0 = 0; a0 < 2 * CH; a0 += NA) {
      int na = (2 * CH - a0) < NA ? (2 * CH - a0) : NA;
      cfix_kernel<<<dim3(400, na), blk, 0, stream>>>(PQ, embz, a0, cfx);
      logits128<<<dim3(13, 13, na), blk, 0, stream>>>(PQ, PKf, cfx, a0, Lg);
      softmax_kernel<<<dim3(LL2, na), blk, 0, stream>>>(Lg);
      av128<<<dim3(13, 4, na), blk, 0, stream>>>(Lg, PVt, PQ, Outb, h0, CH, a0);
    }
  }

  final128<<<dim3(25, 4), blk, 0, stream>>>(Outb, WdB, bd, PX, Y);
  ln_kernel<<<dim3(Bb * LL2), blk, 0, stream>>>(Y, gamma, beta, outp);
}